// Round 2
// baseline (585.863 us; speedup 1.0000x reference)
//
#include <hip/hip_runtime.h>
#include <math.h>

// Problem constants (B=16, S=2048, L=E=512, N=2048)
#define BS_TOK 32768
#define DIM 512
#define NCODE 2048

typedef _Float16 f16x8 __attribute__((ext_vector_type(8)));
typedef _Float16 f16x4 __attribute__((ext_vector_type(4)));
typedef float f32x16 __attribute__((ext_vector_type(16)));

#define LDH 40  // halves per LDS row: 32 data + 8 pad = 80 B

// raw barrier + explicit LDS fence: does NOT drain vmcnt, so prefetch
// global loads stay in flight across the barrier (T3/T4 counted-wait idea).
#define LGKM0_FENCE asm volatile("s_waitcnt lgkmcnt(0)" ::: "memory")
#define SBAR __builtin_amdgcn_s_barrier()

// ---------------- row L2 normalize + fp16 hi/lo split ----------------
__global__ __launch_bounds__(256) void k_rownorm_split(
    const float* __restrict__ in, _Float16* __restrict__ hi,
    _Float16* __restrict__ lo, int rstride) {
  const int r = blockIdx.x;
  const int t = threadIdx.x;
  const float* row = in + (size_t)r * DIM;
  float v0 = row[t];
  float v1 = row[t + 256];
  float s = v0 * v0 + v1 * v1;
#pragma unroll
  for (int off = 32; off > 0; off >>= 1) s += __shfl_down(s, off, 64);
  __shared__ float ls[4];
  if ((t & 63) == 0) ls[t >> 6] = s;
  __syncthreads();  // also fences: all global reads of this row are done
  float tot = ls[0] + ls[1] + ls[2] + ls[3];
  float sc = 1.0f / fmaxf(sqrtf(tot), 1e-12f);
  float x0 = v0 * sc, x1 = v1 * sc;
  _Float16 h0 = (_Float16)x0;
  _Float16 h1 = (_Float16)x1;
  _Float16 e0 = (_Float16)((x0 - (float)h0) * 2048.0f);
  _Float16 e1 = (_Float16)((x1 - (float)h1) * 2048.0f);
  _Float16* hrow = hi + (size_t)r * rstride;
  _Float16* lrow = lo + (size_t)r * rstride;
  hrow[t] = h0;
  hrow[t + 256] = h1;
  lrow[t] = e0;
  lrow[t + 256] = e1;
}

// ---------------- fp32 -> fp16 hi/lo elementwise split (weights) ------
__global__ __launch_bounds__(256) void k_split_w(const float* __restrict__ w,
                                                 _Float16* __restrict__ hi,
                                                 _Float16* __restrict__ lo) {
  int t = (blockIdx.x * 256 + threadIdx.x) * 4;
  float4 v = *(const float4*)(w + t);
  f16x4 h, l;
  h.x = (_Float16)v.x; l.x = (_Float16)((v.x - (float)h.x) * 2048.0f);
  h.y = (_Float16)v.y; l.y = (_Float16)((v.y - (float)h.y) * 2048.0f);
  h.z = (_Float16)v.z; l.z = (_Float16)((v.z - (float)h.z) * 2048.0f);
  h.w = (_Float16)v.w; l.w = (_Float16)((v.w - (float)h.w) * 2048.0f);
  *(f16x4*)(hi + t) = h;
  *(f16x4*)(lo + t) = l;
}

// ---------------- MFMA split GEMM: input projection -------------------
// Pipelined: reg-staged loads issued 1 K-step early; ds_write to the other
// buffer at iter top; one raw barrier per K-step (no vmcnt drain).
__global__ __launch_bounds__(256, 2) void k_gemm_mfma_in(
    const float* __restrict__ A, const _Float16* __restrict__ Bhi,
    const _Float16* __restrict__ Blo, const float* __restrict__ bias,
    float* __restrict__ C) {
  __shared__ __align__(16) _Float16 sm[2][4][128 * LDH];  // 81920 B, 2 blk/CU
  const int tid = threadIdx.x;
  const int w = tid >> 6, l = tid & 63;
  const int wm = w >> 1, wn = w & 1;
  const int lm = l & 31, lh = l >> 5;
  const int m0 = blockIdx.y * 128;
  const int n0 = blockIdx.x * 128;
  // fixed staging map
  const int arow = tid >> 3;        // A rows arow+32i, fp32 col ac4
  const int ac4 = (tid & 7) << 2;
  const int brow = tid >> 2;        // B rows brow+64i, half col bq
  const int bq = (tid & 3) << 3;

  f32x16 aHH[2][2], aX[2][2];
#pragma unroll
  for (int mb = 0; mb < 2; ++mb)
#pragma unroll
    for (int nb = 0; nb < 2; ++nb) {
      aHH[mb][nb] = (f32x16)0.0f;
      aX[mb][nb] = (f32x16)0.0f;
    }

  float4 ar[4];
  f16x8 brh[2], brl[2];

  auto LOADS = [&](int kt) {
#pragma unroll
    for (int i = 0; i < 4; ++i)
      ar[i] =
          *(const float4*)(A + (size_t)(m0 + arow + 32 * i) * DIM + kt * 32 + ac4);
#pragma unroll
    for (int i = 0; i < 2; ++i) {
      const size_t g = (size_t)(n0 + brow + 64 * i) * DIM + kt * 32 + bq;
      brh[i] = *(const f16x8*)(Bhi + g);
      brl[i] = *(const f16x8*)(Blo + g);
    }
  };
  auto WRITES = [&](int b) {
#pragma unroll
    for (int i = 0; i < 4; ++i) {
      f16x4 h, lo4;
      h.x = (_Float16)ar[i].x; lo4.x = (_Float16)((ar[i].x - (float)h.x) * 2048.0f);
      h.y = (_Float16)ar[i].y; lo4.y = (_Float16)((ar[i].y - (float)h.y) * 2048.0f);
      h.z = (_Float16)ar[i].z; lo4.z = (_Float16)((ar[i].z - (float)h.z) * 2048.0f);
      h.w = (_Float16)ar[i].w; lo4.w = (_Float16)((ar[i].w - (float)h.w) * 2048.0f);
      *(f16x4*)(&sm[b][0][(arow + 32 * i) * LDH + ac4]) = h;
      *(f16x4*)(&sm[b][1][(arow + 32 * i) * LDH + ac4]) = lo4;
    }
#pragma unroll
    for (int i = 0; i < 2; ++i) {
      *(f16x8*)(&sm[b][2][(brow + 64 * i) * LDH + bq]) = brh[i];
      *(f16x8*)(&sm[b][3][(brow + 64 * i) * LDH + bq]) = brl[i];
    }
  };

  // prologue
  LOADS(0);
  WRITES(0);  // compiler inserts vmcnt wait for staged regs
  LOADS(1);
  LGKM0_FENCE;
  SBAR;
  int cur = 0;
  const int NT = DIM / 32;  // 16
  for (int t = 0; t < NT; ++t) {
    if (t < NT - 1) WRITES(cur ^ 1);   // data for K-step t+1
    if (t < NT - 2) LOADS(t + 2);      // prefetch, stays in flight past SBAR
#pragma unroll
    for (int c = 0; c < 2; ++c) {
      const int ko = c * 16 + lh * 8;
      f16x8 ah[2], al[2], bh[2], bl[2];
#pragma unroll
      for (int mb = 0; mb < 2; ++mb) {
        int r = wm * 64 + mb * 32 + lm;
        ah[mb] = *(const f16x8*)(&sm[cur][0][r * LDH + ko]);
        al[mb] = *(const f16x8*)(&sm[cur][1][r * LDH + ko]);
      }
#pragma unroll
      for (int nb = 0; nb < 2; ++nb) {
        int r = wn * 64 + nb * 32 + lm;
        bh[nb] = *(const f16x8*)(&sm[cur][2][r * LDH + ko]);
        bl[nb] = *(const f16x8*)(&sm[cur][3][r * LDH + ko]);
      }
#pragma unroll
      for (int mb = 0; mb < 2; ++mb)
#pragma unroll
        for (int nb = 0; nb < 2; ++nb) {
          aHH[mb][nb] = __builtin_amdgcn_mfma_f32_32x32x16_f16(
              ah[mb], bh[nb], aHH[mb][nb], 0, 0, 0);
          aX[mb][nb] = __builtin_amdgcn_mfma_f32_32x32x16_f16(
              ah[mb], bl[nb], aX[mb][nb], 0, 0, 0);
          aX[mb][nb] = __builtin_amdgcn_mfma_f32_32x32x16_f16(
              al[mb], bh[nb], aX[mb][nb], 0, 0, 0);
        }
    }
    LGKM0_FENCE;  // my ds_writes/reads complete before the barrier
    SBAR;
    cur ^= 1;
  }
#pragma unroll
  for (int nb = 0; nb < 2; ++nb) {
    int n = n0 + wn * 64 + nb * 32 + lm;
    float bv = bias[n];
#pragma unroll
    for (int mb = 0; mb < 2; ++mb)
#pragma unroll
      for (int r = 0; r < 16; ++r) {
        int m = m0 + wm * 64 + mb * 32 + (r & 3) + 8 * (r >> 2) + 4 * lh;
        C[(size_t)m * DIM + n] =
            aHH[mb][nb][r] + aX[mb][nb][r] * (1.0f / 2048.0f) + bv;
      }
  }
}

// ---------------- MFMA split GEMM: gathered output projection ---------
// Same pipeline. gidx LDS array replaced by 2 per-thread regs (staging rows
// are fixed per thread) so LDS stays 81920 B -> 2 blocks/CU.
__global__ __launch_bounds__(256, 2) void k_gemm_mfma_gather(
    const _Float16* __restrict__ Ahi, const _Float16* __restrict__ Alo,
    const _Float16* __restrict__ Bhi, const _Float16* __restrict__ Blo,
    const float* __restrict__ bias, float* __restrict__ C,
    const int* __restrict__ gather, const float* __restrict__ zin) {
  __shared__ __align__(16) _Float16 sm[2][4][128 * LDH];  // 81920 B
  const int tid = threadIdx.x;
  const int w = tid >> 6, l = tid & 63;
  const int wm = w >> 1, wn = w & 1;
  const int lm = l & 31, lh = l >> 5;
  const int m0 = blockIdx.y * 128;
  const int n0 = blockIdx.x * 128;
  const int brow = tid >> 2;
  const int bq = (tid & 3) << 3;
  const size_t g0 = (size_t)gather[m0 + brow] * DIM;
  const size_t g1 = (size_t)gather[m0 + 64 + brow] * DIM;

  f32x16 aHH[2][2], aX[2][2];
#pragma unroll
  for (int mb = 0; mb < 2; ++mb)
#pragma unroll
    for (int nb = 0; nb < 2; ++nb) {
      aHH[mb][nb] = (f32x16)0.0f;
      aX[mb][nb] = (f32x16)0.0f;
    }

  f16x8 arh[2], arl[2], brh[2], brl[2];

  auto LOADS = [&](int kt) {
    const int kc = kt * 32 + bq;
    arh[0] = *(const f16x8*)(Ahi + g0 + kc);
    arl[0] = *(const f16x8*)(Alo + g0 + kc);
    arh[1] = *(const f16x8*)(Ahi + g1 + kc);
    arl[1] = *(const f16x8*)(Alo + g1 + kc);
#pragma unroll
    for (int i = 0; i < 2; ++i) {
      const size_t g = (size_t)(n0 + brow + 64 * i) * DIM + kc;
      brh[i] = *(const f16x8*)(Bhi + g);
      brl[i] = *(const f16x8*)(Blo + g);
    }
  };
  auto WRITES = [&](int b) {
#pragma unroll
    for (int i = 0; i < 2; ++i) {
      *(f16x8*)(&sm[b][0][(brow + 64 * i) * LDH + bq]) = arh[i];
      *(f16x8*)(&sm[b][1][(brow + 64 * i) * LDH + bq]) = arl[i];
      *(f16x8*)(&sm[b][2][(brow + 64 * i) * LDH + bq]) = brh[i];
      *(f16x8*)(&sm[b][3][(brow + 64 * i) * LDH + bq]) = brl[i];
    }
  };

  LOADS(0);
  WRITES(0);
  LOADS(1);
  LGKM0_FENCE;
  SBAR;
  int cur = 0;
  const int NT = DIM / 32;
  for (int t = 0; t < NT; ++t) {
    if (t < NT - 1) WRITES(cur ^ 1);
    if (t < NT - 2) LOADS(t + 2);
#pragma unroll
    for (int c = 0; c < 2; ++c) {
      const int ko = c * 16 + lh * 8;
      f16x8 ah[2], al[2], bh[2], bl[2];
#pragma unroll
      for (int mb = 0; mb < 2; ++mb) {
        int r = wm * 64 + mb * 32 + lm;
        ah[mb] = *(const f16x8*)(&sm[cur][0][r * LDH + ko]);
        al[mb] = *(const f16x8*)(&sm[cur][1][r * LDH + ko]);
      }
#pragma unroll
      for (int nb = 0; nb < 2; ++nb) {
        int r = wn * 64 + nb * 32 + lm;
        bh[nb] = *(const f16x8*)(&sm[cur][2][r * LDH + ko]);
        bl[nb] = *(const f16x8*)(&sm[cur][3][r * LDH + ko]);
      }
#pragma unroll
      for (int mb = 0; mb < 2; ++mb)
#pragma unroll
        for (int nb = 0; nb < 2; ++nb) {
          aHH[mb][nb] = __builtin_amdgcn_mfma_f32_32x32x16_f16(
              ah[mb], bh[nb], aHH[mb][nb], 0, 0, 0);
          aX[mb][nb] = __builtin_amdgcn_mfma_f32_32x32x16_f16(
              ah[mb], bl[nb], aX[mb][nb], 0, 0, 0);
          aX[mb][nb] = __builtin_amdgcn_mfma_f32_32x32x16_f16(
              al[mb], bh[nb], aX[mb][nb], 0, 0, 0);
        }
    }
    LGKM0_FENCE;
    SBAR;
    cur ^= 1;
  }
#pragma unroll
  for (int nb = 0; nb < 2; ++nb) {
    int n = n0 + wn * 64 + nb * 32 + lm;
    float bv = bias[n];
#pragma unroll
    for (int mb = 0; mb < 2; ++mb)
#pragma unroll
      for (int r = 0; r < 16; ++r) {
        int m = m0 + wm * 64 + mb * 32 + (r & 3) + 8 * (r >> 2) + 4 * lh;
        float val = aHH[mb][nb][r] + aX[mb][nb][r] * (1.0f / 2048.0f) + bv;
        float zv = zin[(size_t)m * DIM + n];
        C[(size_t)m * DIM + n] = zv + (val - zv);
      }
  }
}

// ---------------- MFMA similarity + argmax ----------------------------
// A fragments loaded DIRECTLY global->VGPR (layout matches the MFMA A
// operand: lane holds row l&31, cols (l>>5)*8). Only B (codes) goes through
// LDS, double-buffered, single raw barrier per K-step. LDS 40960 B.
#define SIMK_BM 128
#define SIMK_BN 128

__global__ __launch_bounds__(256, 2) void k_sim_argmax(
    const _Float16* __restrict__ Apack,  // token rows: 1024 halves = hi|lo
    const _Float16* __restrict__ Bhi, const _Float16* __restrict__ Blo,
    unsigned long long* __restrict__ keys) {
  __shared__ __align__(16) _Float16 sm[2][2][128 * LDH];  // 40960 B
  float* sC = (float*)sm;  // epilogue alias: [128][65] fp32 = 33280 B

  const int tid = threadIdx.x;
  const int w = tid >> 6, l = tid & 63;
  const int wm = w >> 1, wn = w & 1;
  const int lm = l & 31, lh = l >> 5;
  const int s = blockIdx.x & 1;
  const int tokbase = (blockIdx.x >> 1) * SIMK_BM;
  const int code0 = s * (NCODE / 2);
  const int brow = tid >> 2;
  const int bq = (tid & 3) << 3;
  const int t_red = tid >> 1, h_red = tid & 1;

  // per-lane direct A bases (mb = 0,1)
  const _Float16* aA0 =
      Apack + (size_t)(tokbase + wm * 64 + lm) * 1024 + lh * 8;
  const _Float16* aA1 = aA0 + 32 * 1024;

  float bestv = -2.0f;
  int bestn = 0;

  f16x8 brh[2], brl[2];

  auto LOADB = [&](int nt, int kt) {
    const int kc = kt * 32 + bq;
#pragma unroll
    for (int i = 0; i < 2; ++i) {
      const size_t g = (size_t)(code0 + nt + brow + 64 * i) * DIM + kc;
      brh[i] = *(const f16x8*)(Bhi + g);
      brl[i] = *(const f16x8*)(Blo + g);
    }
  };
  auto WRITEB = [&](int b) {
#pragma unroll
    for (int i = 0; i < 2; ++i) {
      *(f16x8*)(&sm[b][0][(brow + 64 * i) * LDH + bq]) = brh[i];
      *(f16x8*)(&sm[b][1][(brow + 64 * i) * LDH + bq]) = brl[i];
    }
  };

  for (int nt = 0; nt < NCODE / 2; nt += SIMK_BN) {
    f32x16 aHH[2][2], aX[2][2];
#pragma unroll
    for (int mb = 0; mb < 2; ++mb)
#pragma unroll
      for (int nb = 0; nb < 2; ++nb) {
        aHH[mb][nb] = (f32x16)0.0f;
        aX[mb][nb] = (f32x16)0.0f;
      }
    __syncthreads();  // prev epilogue's sC reads done before restaging
    LOADB(nt, 0);
    WRITEB(0);
    LOADB(nt, 1);
    LGKM0_FENCE;
    SBAR;
    int cur = 0;
    for (int t = 0; t < 16; ++t) {
      // A fragments: direct global loads (issued first, max latency cover)
      f16x8 gah[2][2], gal[2][2];
#pragma unroll
      for (int c = 0; c < 2; ++c) {
        gah[c][0] = *(const f16x8*)(aA0 + t * 32 + c * 16);
        gal[c][0] = *(const f16x8*)(aA0 + 512 + t * 32 + c * 16);
        gah[c][1] = *(const f16x8*)(aA1 + t * 32 + c * 16);
        gal[c][1] = *(const f16x8*)(aA1 + 512 + t * 32 + c * 16);
      }
      if (t < 15) WRITEB(cur ^ 1);   // B data for K-step t+1
      if (t < 14) LOADB(nt, t + 2);  // prefetch, survives the barrier
#pragma unroll
      for (int c = 0; c < 2; ++c) {
        const int ko = c * 16 + lh * 8;
        f16x8 bh[2], bl[2];
#pragma unroll
        for (int nb = 0; nb < 2; ++nb) {
          int r = wn * 64 + nb * 32 + lm;
          bh[nb] = *(const f16x8*)(&sm[cur][0][r * LDH + ko]);
          bl[nb] = *(const f16x8*)(&sm[cur][1][r * LDH + ko]);
        }
#pragma unroll
        for (int mb = 0; mb < 2; ++mb)
#pragma unroll
          for (int nb = 0; nb < 2; ++nb) {
            aHH[mb][nb] = __builtin_amdgcn_mfma_f32_32x32x16_f16(
                gah[c][mb], bh[nb], aHH[mb][nb], 0, 0, 0);
            aX[mb][nb] = __builtin_amdgcn_mfma_f32_32x32x16_f16(
                gah[c][mb], bl[nb], aX[mb][nb], 0, 0, 0);
            aX[mb][nb] = __builtin_amdgcn_mfma_f32_32x32x16_f16(
                gal[c][mb], bh[nb], aX[mb][nb], 0, 0, 0);
          }
      }
      LGKM0_FENCE;
      SBAR;
      cur ^= 1;
    }
    // epilogue: two n-halves through LDS (aliased over staging region)
#pragma unroll
    for (int p = 0; p < 2; ++p) {
      __syncthreads();
      if (wn == p) {
#pragma unroll
        for (int mb = 0; mb < 2; ++mb)
#pragma unroll
          for (int nb = 0; nb < 2; ++nb) {
            int nl = nb * 32 + lm;
#pragma unroll
            for (int r = 0; r < 16; ++r) {
              int m = wm * 64 + mb * 32 + (r & 3) + 8 * (r >> 2) + 4 * lh;
              float v = aHH[mb][nb][r] + aX[mb][nb][r] * (1.0f / 2048.0f);
              sC[m * 65 + nl] = v;
            }
          }
      }
      __syncthreads();
      const float* rowp = &sC[t_red * 65 + h_red * 32];
      int nbase = code0 + nt + p * 64 + h_red * 32;
#pragma unroll
      for (int i = 0; i < 32; ++i) {
        float v = rowp[i];
        if (v > bestv) {  // n scanned ascending: '>' keeps first occurrence
          bestv = v;
          bestn = nbase + i;
        }
      }
    }
  }
  // combine the two half-lanes for this token
  float ov = __shfl_xor(bestv, 1);
  int on = __shfl_xor(bestn, 1);
  if (ov > bestv || (ov == bestv && on < bestn)) {
    bestv = ov;
    bestn = on;
  }
  if (h_red == 0) {
    // monotone float encoding: larger key == larger value; low word
    // NCODE-1-n so equal values pick the smaller index (first occurrence).
    unsigned vb = __float_as_uint(bestv);
    vb = (vb & 0x80000000u) ? ~vb : (vb | 0x80000000u);
    unsigned long long key =
        ((unsigned long long)vb << 32) | (unsigned)(NCODE - 1 - bestn);
    atomicMax(&keys[tokbase + t_red], key);
  }
}

// ---------------- init packed argmax keys ----------------------------
__global__ __launch_bounds__(256) void k_init_keys(
    unsigned long long* __restrict__ keys) {
  keys[blockIdx.x * 256 + threadIdx.x] = 0ull;  // < any real encoded sim
}

// ---------------- decode packed keys -> idx (int) + idxf (float) ------
__global__ __launch_bounds__(256) void k_decode(
    const unsigned long long* __restrict__ keys, int* __restrict__ idx,
    float* __restrict__ idxf) {
  int t = blockIdx.x * 256 + threadIdx.x;
  int n = NCODE - 1 - (int)(keys[t] & 0xFFFFFFFFull);
  idx[t] = n;
  idxf[t] = (float)n;
}

extern "C" void kernel_launch(void* const* d_in, const int* in_sizes, int n_in,
                              void* d_out, int out_size, void* d_ws,
                              size_t ws_size, hipStream_t stream) {
  const float* z = (const float*)d_in[0];
  // d_in[1] = mask, unused
  const float* W_in = (const float*)d_in[2];
  const float* b_in = (const float*)d_in[3];
  const float* W_out = (const float*)d_in[4];
  const float* b_out = (const float*)d_in[5];
  const float* emb = (const float*)d_in[6];

  float* out = (float*)d_out;
  float* zq = out;                           // 32768*512 fp32 (final output)
  float* idxf = out + (size_t)BS_TOK * DIM;  // 32768 fp32 indices

  // ws layout (~6.4 MB): embhi|emblo|winhi|winlo|wouthi|woutlo|keys|idx
  _Float16* embhi = (_Float16*)d_ws;
  _Float16* emblo = embhi + (size_t)NCODE * DIM;
  _Float16* winhi = emblo + (size_t)NCODE * DIM;
  _Float16* winlo = winhi + (size_t)DIM * DIM;
  _Float16* wouthi = winlo + (size_t)DIM * DIM;
  _Float16* woutlo = wouthi + (size_t)DIM * DIM;
  unsigned long long* keys =
      (unsigned long long*)(woutlo + (size_t)DIM * DIM);  // 8B-aligned
  int* idx = (int*)(keys + (size_t)BS_TOK);

  // zf fp32 lives in the zq region; then packed in-place to fp16 hi|lo rows
  float* zf = zq;
  _Float16* zf16 = (_Float16*)zf;  // row stride 1024 halves: [hi 512|lo 512]

  // 0) init argmax keys + split weights
  k_init_keys<<<BS_TOK / 256, 256, 0, stream>>>(keys);
  k_split_w<<<DIM * DIM / 1024, 256, 0, stream>>>(W_in, winhi, winlo);
  k_split_w<<<DIM * DIM / 1024, 256, 0, stream>>>(W_out, wouthi, woutlo);
  // 1) normalize + split codebook rows -> ws
  k_rownorm_split<<<NCODE, 256, 0, stream>>>(emb, embhi, emblo, DIM);
  // 2) zf = z @ W_in^T + b_in (MFMA fp16-split, A converted on the fly)
  k_gemm_mfma_in<<<dim3(DIM / 128, BS_TOK / 128), 256, 0, stream>>>(
      z, winhi, winlo, b_in, zf);
  // 3) normalize zf rows, split to fp16 hi/lo IN-PLACE (packed rows)
  k_rownorm_split<<<BS_TOK, 256, 0, stream>>>(zf, zf16, zf16 + 512, 1024);
  // 4) MFMA similarity + argmax (2 code-halves per token tile)
  k_sim_argmax<<<(BS_TOK / SIMK_BM) * 2, 256, 0, stream>>>(zf16, embhi, emblo,
                                                           keys);
  // 5) decode packed keys -> idx (ws) + idxf (d_out)
  k_decode<<<BS_TOK / 256, 256, 0, stream>>>(keys, idx, idxf);
  // 6) zq = emb_n[idx] @ W_out^T + b_out (+ straight-through), overwrites zf
  k_gemm_mfma_gather<<<dim3(DIM / 128, BS_TOK / 128), 256, 0, stream>>>(
      embhi, emblo, wouthi, woutlo, b_out, zq, idx, z);
}

// Round 4
// 529.276 us; speedup vs baseline: 1.1069x; 1.1069x over previous
//
#include <hip/hip_runtime.h>
#include <math.h>

// Problem constants (B=16, S=2048, L=E=512, N=2048)
#define BS_TOK 32768
#define DIM 512
#define NCODE 2048

typedef _Float16 f16x8 __attribute__((ext_vector_type(8)));
typedef _Float16 f16x4 __attribute__((ext_vector_type(4)));
typedef float f32x16 __attribute__((ext_vector_type(16)));

#define LDH 40  // halves per LDS row: 32 data + 8 pad = 80 B

// raw barrier + explicit LDS fence: does NOT drain vmcnt, so prefetch
// global loads stay in flight across the barrier (T3/T4 counted-wait idea).
#define LGKM0_FENCE asm volatile("s_waitcnt lgkmcnt(0)" ::: "memory")
#define SBAR __builtin_amdgcn_s_barrier()

// ---------------- row L2 normalize + fp16 hi/lo split ----------------
__global__ __launch_bounds__(256) void k_rownorm_split(
    const float* __restrict__ in, _Float16* __restrict__ hi,
    _Float16* __restrict__ lo, int rstride) {
  const int r = blockIdx.x;
  const int t = threadIdx.x;
  const float* row = in + (size_t)r * DIM;
  float v0 = row[t];
  float v1 = row[t + 256];
  float s = v0 * v0 + v1 * v1;
#pragma unroll
  for (int off = 32; off > 0; off >>= 1) s += __shfl_down(s, off, 64);
  __shared__ float ls[4];
  if ((t & 63) == 0) ls[t >> 6] = s;
  __syncthreads();  // also fences: all global reads of this row are done
  float tot = ls[0] + ls[1] + ls[2] + ls[3];
  float sc = 1.0f / fmaxf(sqrtf(tot), 1e-12f);
  float x0 = v0 * sc, x1 = v1 * sc;
  _Float16 h0 = (_Float16)x0;
  _Float16 h1 = (_Float16)x1;
  _Float16 e0 = (_Float16)((x0 - (float)h0) * 2048.0f);
  _Float16 e1 = (_Float16)((x1 - (float)h1) * 2048.0f);
  _Float16* hrow = hi + (size_t)r * rstride;
  _Float16* lrow = lo + (size_t)r * rstride;
  hrow[t] = h0;
  hrow[t + 256] = h1;
  lrow[t] = e0;
  lrow[t + 256] = e1;
}

// ---------------- fp32 -> fp16 hi/lo elementwise split (weights) ------
__global__ __launch_bounds__(256) void k_split_w(const float* __restrict__ w,
                                                 _Float16* __restrict__ hi,
                                                 _Float16* __restrict__ lo) {
  int t = (blockIdx.x * 256 + threadIdx.x) * 4;
  float4 v = *(const float4*)(w + t);
  f16x4 h, l;
  h.x = (_Float16)v.x; l.x = (_Float16)((v.x - (float)h.x) * 2048.0f);
  h.y = (_Float16)v.y; l.y = (_Float16)((v.y - (float)h.y) * 2048.0f);
  h.z = (_Float16)v.z; l.z = (_Float16)((v.z - (float)h.z) * 2048.0f);
  h.w = (_Float16)v.w; l.w = (_Float16)((v.w - (float)h.w) * 2048.0f);
  *(f16x4*)(hi + t) = h;
  *(f16x4*)(lo + t) = l;
}

// ---------------- MFMA split GEMM: input projection -------------------
// Pipelined: reg-staged loads issued 1 K-step early; ds_write to the other
// buffer at iter top; one raw barrier per K-step (no vmcnt drain).
__global__ __launch_bounds__(256, 2) void k_gemm_mfma_in(
    const float* __restrict__ A, const _Float16* __restrict__ Bhi,
    const _Float16* __restrict__ Blo, const float* __restrict__ bias,
    float* __restrict__ C) {
  __shared__ __align__(16) _Float16 sm[2][4][128 * LDH];  // 81920 B, 2 blk/CU
  const int tid = threadIdx.x;
  const int w = tid >> 6, l = tid & 63;
  const int wm = w >> 1, wn = w & 1;
  const int lm = l & 31, lh = l >> 5;
  const int m0 = blockIdx.y * 128;
  const int n0 = blockIdx.x * 128;
  // fixed staging map
  const int arow = tid >> 3;        // A rows arow+32i, fp32 col ac4
  const int ac4 = (tid & 7) << 2;
  const int brow = tid >> 2;        // B rows brow+64i, half col bq
  const int bq = (tid & 3) << 3;

  f32x16 aHH[2][2], aX[2][2];
#pragma unroll
  for (int mb = 0; mb < 2; ++mb)
#pragma unroll
    for (int nb = 0; nb < 2; ++nb) {
      aHH[mb][nb] = (f32x16)0.0f;
      aX[mb][nb] = (f32x16)0.0f;
    }

  float4 ar[4];
  f16x8 brh[2], brl[2];

  auto LOADS = [&](int kt) {
#pragma unroll
    for (int i = 0; i < 4; ++i)
      ar[i] =
          *(const float4*)(A + (size_t)(m0 + arow + 32 * i) * DIM + kt * 32 + ac4);
#pragma unroll
    for (int i = 0; i < 2; ++i) {
      const size_t g = (size_t)(n0 + brow + 64 * i) * DIM + kt * 32 + bq;
      brh[i] = *(const f16x8*)(Bhi + g);
      brl[i] = *(const f16x8*)(Blo + g);
    }
  };
  auto WRITES = [&](int b) {
#pragma unroll
    for (int i = 0; i < 4; ++i) {
      f16x4 h, lo4;
      h.x = (_Float16)ar[i].x; lo4.x = (_Float16)((ar[i].x - (float)h.x) * 2048.0f);
      h.y = (_Float16)ar[i].y; lo4.y = (_Float16)((ar[i].y - (float)h.y) * 2048.0f);
      h.z = (_Float16)ar[i].z; lo4.z = (_Float16)((ar[i].z - (float)h.z) * 2048.0f);
      h.w = (_Float16)ar[i].w; lo4.w = (_Float16)((ar[i].w - (float)h.w) * 2048.0f);
      *(f16x4*)(&sm[b][0][(arow + 32 * i) * LDH + ac4]) = h;
      *(f16x4*)(&sm[b][1][(arow + 32 * i) * LDH + ac4]) = lo4;
    }
#pragma unroll
    for (int i = 0; i < 2; ++i) {
      *(f16x8*)(&sm[b][2][(brow + 64 * i) * LDH + bq]) = brh[i];
      *(f16x8*)(&sm[b][3][(brow + 64 * i) * LDH + bq]) = brl[i];
    }
  };

  // prologue
  LOADS(0);
  WRITES(0);  // compiler inserts vmcnt wait for staged regs
  LOADS(1);
  LGKM0_FENCE;
  SBAR;
  int cur = 0;
  const int NT = DIM / 32;  // 16
  for (int t = 0; t < NT; ++t) {
    if (t < NT - 1) WRITES(cur ^ 1);   // data for K-step t+1
    if (t < NT - 2) LOADS(t + 2);      // prefetch, stays in flight past SBAR
#pragma unroll
    for (int c = 0; c < 2; ++c) {
      const int ko = c * 16 + lh * 8;
      f16x8 ah[2], al[2], bh[2], bl[2];
#pragma unroll
      for (int mb = 0; mb < 2; ++mb) {
        int r = wm * 64 + mb * 32 + lm;
        ah[mb] = *(const f16x8*)(&sm[cur][0][r * LDH + ko]);
        al[mb] = *(const f16x8*)(&sm[cur][1][r * LDH + ko]);
      }
#pragma unroll
      for (int nb = 0; nb < 2; ++nb) {
        int r = wn * 64 + nb * 32 + lm;
        bh[nb] = *(const f16x8*)(&sm[cur][2][r * LDH + ko]);
        bl[nb] = *(const f16x8*)(&sm[cur][3][r * LDH + ko]);
      }
#pragma unroll
      for (int mb = 0; mb < 2; ++mb)
#pragma unroll
        for (int nb = 0; nb < 2; ++nb) {
          aHH[mb][nb] = __builtin_amdgcn_mfma_f32_32x32x16_f16(
              ah[mb], bh[nb], aHH[mb][nb], 0, 0, 0);
          aX[mb][nb] = __builtin_amdgcn_mfma_f32_32x32x16_f16(
              ah[mb], bl[nb], aX[mb][nb], 0, 0, 0);
          aX[mb][nb] = __builtin_amdgcn_mfma_f32_32x32x16_f16(
              al[mb], bh[nb], aX[mb][nb], 0, 0, 0);
        }
    }
    LGKM0_FENCE;  // my ds_writes/reads complete before the barrier
    SBAR;
    cur ^= 1;
  }
#pragma unroll
  for (int nb = 0; nb < 2; ++nb) {
    int n = n0 + wn * 64 + nb * 32 + lm;
    float bv = bias[n];
#pragma unroll
    for (int mb = 0; mb < 2; ++mb)
#pragma unroll
      for (int r = 0; r < 16; ++r) {
        int m = m0 + wm * 64 + mb * 32 + (r & 3) + 8 * (r >> 2) + 4 * lh;
        C[(size_t)m * DIM + n] =
            aHH[mb][nb][r] + aX[mb][nb][r] * (1.0f / 2048.0f) + bv;
      }
  }
}

// ---------------- MFMA split GEMM: gathered output projection ---------
// Same pipeline. gidx LDS array replaced by 2 per-thread regs (staging rows
// are fixed per thread) so LDS stays 81920 B -> 2 blocks/CU.
__global__ __launch_bounds__(256, 2) void k_gemm_mfma_gather(
    const _Float16* __restrict__ Ahi, const _Float16* __restrict__ Alo,
    const _Float16* __restrict__ Bhi, const _Float16* __restrict__ Blo,
    const float* __restrict__ bias, float* __restrict__ C,
    const int* __restrict__ gather, const float* __restrict__ zin) {
  __shared__ __align__(16) _Float16 sm[2][4][128 * LDH];  // 81920 B
  const int tid = threadIdx.x;
  const int w = tid >> 6, l = tid & 63;
  const int wm = w >> 1, wn = w & 1;
  const int lm = l & 31, lh = l >> 5;
  const int m0 = blockIdx.y * 128;
  const int n0 = blockIdx.x * 128;
  const int brow = tid >> 2;
  const int bq = (tid & 3) << 3;
  const size_t g0 = (size_t)gather[m0 + brow] * DIM;
  const size_t g1 = (size_t)gather[m0 + 64 + brow] * DIM;

  f32x16 aHH[2][2], aX[2][2];
#pragma unroll
  for (int mb = 0; mb < 2; ++mb)
#pragma unroll
    for (int nb = 0; nb < 2; ++nb) {
      aHH[mb][nb] = (f32x16)0.0f;
      aX[mb][nb] = (f32x16)0.0f;
    }

  f16x8 arh[2], arl[2], brh[2], brl[2];

  auto LOADS = [&](int kt) {
    const int kc = kt * 32 + bq;
    arh[0] = *(const f16x8*)(Ahi + g0 + kc);
    arl[0] = *(const f16x8*)(Alo + g0 + kc);
    arh[1] = *(const f16x8*)(Ahi + g1 + kc);
    arl[1] = *(const f16x8*)(Alo + g1 + kc);
#pragma unroll
    for (int i = 0; i < 2; ++i) {
      const size_t g = (size_t)(n0 + brow + 64 * i) * DIM + kc;
      brh[i] = *(const f16x8*)(Bhi + g);
      brl[i] = *(const f16x8*)(Blo + g);
    }
  };
  auto WRITES = [&](int b) {
#pragma unroll
    for (int i = 0; i < 2; ++i) {
      *(f16x8*)(&sm[b][0][(brow + 64 * i) * LDH + bq]) = arh[i];
      *(f16x8*)(&sm[b][1][(brow + 64 * i) * LDH + bq]) = arl[i];
      *(f16x8*)(&sm[b][2][(brow + 64 * i) * LDH + bq]) = brh[i];
      *(f16x8*)(&sm[b][3][(brow + 64 * i) * LDH + bq]) = brl[i];
    }
  };

  LOADS(0);
  WRITES(0);
  LOADS(1);
  LGKM0_FENCE;
  SBAR;
  int cur = 0;
  const int NT = DIM / 32;
  for (int t = 0; t < NT; ++t) {
    if (t < NT - 1) WRITES(cur ^ 1);
    if (t < NT - 2) LOADS(t + 2);
#pragma unroll
    for (int c = 0; c < 2; ++c) {
      const int ko = c * 16 + lh * 8;
      f16x8 ah[2], al[2], bh[2], bl[2];
#pragma unroll
      for (int mb = 0; mb < 2; ++mb) {
        int r = wm * 64 + mb * 32 + lm;
        ah[mb] = *(const f16x8*)(&sm[cur][0][r * LDH + ko]);
        al[mb] = *(const f16x8*)(&sm[cur][1][r * LDH + ko]);
      }
#pragma unroll
      for (int nb = 0; nb < 2; ++nb) {
        int r = wn * 64 + nb * 32 + lm;
        bh[nb] = *(const f16x8*)(&sm[cur][2][r * LDH + ko]);
        bl[nb] = *(const f16x8*)(&sm[cur][3][r * LDH + ko]);
      }
#pragma unroll
      for (int mb = 0; mb < 2; ++mb)
#pragma unroll
        for (int nb = 0; nb < 2; ++nb) {
          aHH[mb][nb] = __builtin_amdgcn_mfma_f32_32x32x16_f16(
              ah[mb], bh[nb], aHH[mb][nb], 0, 0, 0);
          aX[mb][nb] = __builtin_amdgcn_mfma_f32_32x32x16_f16(
              ah[mb], bl[nb], aX[mb][nb], 0, 0, 0);
          aX[mb][nb] = __builtin_amdgcn_mfma_f32_32x32x16_f16(
              al[mb], bh[nb], aX[mb][nb], 0, 0, 0);
        }
    }
    LGKM0_FENCE;
    SBAR;
    cur ^= 1;
  }
#pragma unroll
  for (int nb = 0; nb < 2; ++nb) {
    int n = n0 + wn * 64 + nb * 32 + lm;
    float bv = bias[n];
#pragma unroll
    for (int mb = 0; mb < 2; ++mb)
#pragma unroll
      for (int r = 0; r < 16; ++r) {
        int m = m0 + wm * 64 + mb * 32 + (r & 3) + 8 * (r >> 2) + 4 * lh;
        float val = aHH[mb][nb][r] + aX[mb][nb][r] * (1.0f / 2048.0f) + bv;
        float zv = zin[(size_t)m * DIM + n];
        C[(size_t)m * DIM + n] = zv + (val - zv);
      }
  }
}

// ---------------- MFMA similarity + argmax ----------------------------
// Round-0 data path (A AND B staged through LDS, double-buffered) +
// round-2 pipeline (reg-staged loads 1 K-step early, ds_write to other
// buffer at iter top, ONE raw barrier per K-step, no vmcnt drain).
// LDS 81920 B -> 2 blocks/CU (160 KiB exactly).
#define SIMK_BM 128
#define SIMK_BN 128

__global__ __launch_bounds__(256, 2) void k_sim_argmax(
    const _Float16* __restrict__ Apack,  // token rows: 1024 halves = hi|lo
    const _Float16* __restrict__ Bhi, const _Float16* __restrict__ Blo,
    unsigned long long* __restrict__ keys) {
  __shared__ __align__(16) _Float16 sm[2][4][128 * LDH];  // 81920 B
  float* sC = (float*)sm;  // epilogue alias: [128][65] fp32 = 33280 B

  const int tid = threadIdx.x;
  const int w = tid >> 6, l = tid & 63;
  const int wm = w >> 1, wn = w & 1;
  const int lm = l & 31, lh = l >> 5;
  const int s = blockIdx.x & 1;
  const int tokbase = (blockIdx.x >> 1) * SIMK_BM;
  const int code0 = s * (NCODE / 2);
  const int brow = tid >> 2;
  const int bq = (tid & 3) << 3;
  const int t_red = tid >> 1, h_red = tid & 1;

  float bestv = -2.0f;
  int bestn = 0;

  f16x8 arh[2], arl[2], brh[2], brl[2];

  auto LOADS = [&](int nt, int kt) {
    const int kc = kt * 32 + bq;
#pragma unroll
    for (int i = 0; i < 2; ++i) {
      const size_t ga = (size_t)(tokbase + brow + 64 * i) * 1024 + kc;
      arh[i] = *(const f16x8*)(Apack + ga);
      arl[i] = *(const f16x8*)(Apack + ga + 512);
      const size_t gb = (size_t)(code0 + nt + brow + 64 * i) * DIM + kc;
      brh[i] = *(const f16x8*)(Bhi + gb);
      brl[i] = *(const f16x8*)(Blo + gb);
    }
  };
  auto WRITES = [&](int b) {
#pragma unroll
    for (int i = 0; i < 2; ++i) {
      *(f16x8*)(&sm[b][0][(brow + 64 * i) * LDH + bq]) = arh[i];
      *(f16x8*)(&sm[b][1][(brow + 64 * i) * LDH + bq]) = arl[i];
      *(f16x8*)(&sm[b][2][(brow + 64 * i) * LDH + bq]) = brh[i];
      *(f16x8*)(&sm[b][3][(brow + 64 * i) * LDH + bq]) = brl[i];
    }
  };

  for (int nt = 0; nt < NCODE / 2; nt += SIMK_BN) {
    f32x16 aHH[2][2], aX[2][2];
#pragma unroll
    for (int mb = 0; mb < 2; ++mb)
#pragma unroll
      for (int nb = 0; nb < 2; ++nb) {
        aHH[mb][nb] = (f32x16)0.0f;
        aX[mb][nb] = (f32x16)0.0f;
      }
    __syncthreads();  // prev epilogue's sC reads done before restaging
    LOADS(nt, 0);
    WRITES(0);
    LOADS(nt, 1);
    LGKM0_FENCE;
    SBAR;
    int cur = 0;
    for (int t = 0; t < 16; ++t) {
      if (t < 15) WRITES(cur ^ 1);   // data for K-step t+1
      if (t < 14) LOADS(nt, t + 2);  // prefetch, survives the barrier
#pragma unroll
      for (int c = 0; c < 2; ++c) {
        const int ko = c * 16 + lh * 8;
        f16x8 ah[2], al[2], bh[2], bl[2];
#pragma unroll
        for (int mb = 0; mb < 2; ++mb) {
          int r = wm * 64 + mb * 32 + lm;
          ah[mb] = *(const f16x8*)(&sm[cur][0][r * LDH + ko]);
          al[mb] = *(const f16x8*)(&sm[cur][1][r * LDH + ko]);
        }
#pragma unroll
        for (int nb = 0; nb < 2; ++nb) {
          int r = wn * 64 + nb * 32 + lm;
          bh[nb] = *(const f16x8*)(&sm[cur][2][r * LDH + ko]);
          bl[nb] = *(const f16x8*)(&sm[cur][3][r * LDH + ko]);
        }
#pragma unroll
        for (int mb = 0; mb < 2; ++mb)
#pragma unroll
          for (int nb = 0; nb < 2; ++nb) {
            aHH[mb][nb] = __builtin_amdgcn_mfma_f32_32x32x16_f16(
                ah[mb], bh[nb], aHH[mb][nb], 0, 0, 0);
            aX[mb][nb] = __builtin_amdgcn_mfma_f32_32x32x16_f16(
                ah[mb], bl[nb], aX[mb][nb], 0, 0, 0);
            aX[mb][nb] = __builtin_amdgcn_mfma_f32_32x32x16_f16(
                al[mb], bh[nb], aX[mb][nb], 0, 0, 0);
          }
      }
      LGKM0_FENCE;
      SBAR;
      cur ^= 1;
    }
    // epilogue: two n-halves through LDS (aliased over staging region)
#pragma unroll
    for (int p = 0; p < 2; ++p) {
      __syncthreads();
      if (wn == p) {
#pragma unroll
        for (int mb = 0; mb < 2; ++mb)
#pragma unroll
          for (int nb = 0; nb < 2; ++nb) {
            int nl = nb * 32 + lm;
#pragma unroll
            for (int r = 0; r < 16; ++r) {
              int m = wm * 64 + mb * 32 + (r & 3) + 8 * (r >> 2) + 4 * lh;
              float v = aHH[mb][nb][r] + aX[mb][nb][r] * (1.0f / 2048.0f);
              sC[m * 65 + nl] = v;
            }
          }
      }
      __syncthreads();
      const float* rowp = &sC[t_red * 65 + h_red * 32];
      int nbase = code0 + nt + p * 64 + h_red * 32;
#pragma unroll
      for (int i = 0; i < 32; ++i) {
        float v = rowp[i];
        if (v > bestv) {  // n scanned ascending: '>' keeps first occurrence
          bestv = v;
          bestn = nbase + i;
        }
      }
    }
  }
  // combine the two half-lanes for this token
  float ov = __shfl_xor(bestv, 1);
  int on = __shfl_xor(bestn, 1);
  if (ov > bestv || (ov == bestv && on < bestn)) {
    bestv = ov;
    bestn = on;
  }
  if (h_red == 0) {
    // monotone float encoding: larger key == larger value; low word
    // NCODE-1-n so equal values pick the smaller index (first occurrence).
    unsigned vb = __float_as_uint(bestv);
    vb = (vb & 0x80000000u) ? ~vb : (vb | 0x80000000u);
    unsigned long long key =
        ((unsigned long long)vb << 32) | (unsigned)(NCODE - 1 - bestn);
    atomicMax(&keys[tokbase + t_red], key);
  }
}

// ---------------- init packed argmax keys ----------------------------
__global__ __launch_bounds__(256) void k_init_keys(
    unsigned long long* __restrict__ keys) {
  keys[blockIdx.x * 256 + threadIdx.x] = 0ull;  // < any real encoded sim
}

// ---------------- decode packed keys -> idx (int) + idxf (float) ------
__global__ __launch_bounds__(256) void k_decode(
    const unsigned long long* __restrict__ keys, int* __restrict__ idx,
    float* __restrict__ idxf) {
  int t = blockIdx.x * 256 + threadIdx.x;
  int n = NCODE - 1 - (int)(keys[t] & 0xFFFFFFFFull);
  idx[t] = n;
  idxf[t] = (float)n;
}

extern "C" void kernel_launch(void* const* d_in, const int* in_sizes, int n_in,
                              void* d_out, int out_size, void* d_ws,
                              size_t ws_size, hipStream_t stream) {
  const float* z = (const float*)d_in[0];
  // d_in[1] = mask, unused
  const float* W_in = (const float*)d_in[2];
  const float* b_in = (const float*)d_in[3];
  const float* W_out = (const float*)d_in[4];
  const float* b_out = (const float*)d_in[5];
  const float* emb = (const float*)d_in[6];

  float* out = (float*)d_out;
  float* zq = out;                           // 32768*512 fp32 (final output)
  float* idxf = out + (size_t)BS_TOK * DIM;  // 32768 fp32 indices

  // ws layout (~6.4 MB): embhi|emblo|winhi|winlo|wouthi|woutlo|keys|idx
  _Float16* embhi = (_Float16*)d_ws;
  _Float16* emblo = embhi + (size_t)NCODE * DIM;
  _Float16* winhi = emblo + (size_t)NCODE * DIM;
  _Float16* winlo = winhi + (size_t)DIM * DIM;
  _Float16* wouthi = winlo + (size_t)DIM * DIM;
  _Float16* woutlo = wouthi + (size_t)DIM * DIM;
  unsigned long long* keys =
      (unsigned long long*)(woutlo + (size_t)DIM * DIM);  // 8B-aligned
  int* idx = (int*)(keys + (size_t)BS_TOK);

  // zf fp32 lives in the zq region; then packed in-place to fp16 hi|lo rows
  float* zf = zq;
  _Float16* zf16 = (_Float16*)zf;  // row stride 1024 halves: [hi 512|lo 512]

  // 0) init argmax keys + split weights
  k_init_keys<<<BS_TOK / 256, 256, 0, stream>>>(keys);
  k_split_w<<<DIM * DIM / 1024, 256, 0, stream>>>(W_in, winhi, winlo);
  k_split_w<<<DIM * DIM / 1024, 256, 0, stream>>>(W_out, wouthi, woutlo);
  // 1) normalize + split codebook rows -> ws
  k_rownorm_split<<<NCODE, 256, 0, stream>>>(emb, embhi, emblo, DIM);
  // 2) zf = z @ W_in^T + b_in (MFMA fp16-split, A converted on the fly)
  k_gemm_mfma_in<<<dim3(DIM / 128, BS_TOK / 128), 256, 0, stream>>>(
      z, winhi, winlo, b_in, zf);
  // 3) normalize zf rows, split to fp16 hi/lo IN-PLACE (packed rows)
  k_rownorm_split<<<BS_TOK, 256, 0, stream>>>(zf, zf16, zf16 + 512, 1024);
  // 4) MFMA similarity + argmax (2 code-halves per token tile)
  k_sim_argmax<<<(BS_TOK / SIMK_BM) * 2, 256, 0, stream>>>(zf16, embhi, emblo,
                                                           keys);
  // 5) decode packed keys -> idx (ws) + idxf (d_out)
  k_decode<<<BS_TOK / 256, 256, 0, stream>>>(keys, idx, idxf);
  // 6) zq = emb_n[idx] @ W_out^T + b_out (+ straight-through), overwrites zf
  k_gemm_mfma_gather<<<dim3(DIM / 128, BS_TOK / 128), 256, 0, stream>>>(
      embhi, emblo, wouthi, woutlo, b_out, zq, idx, z);
}

// Round 5
// 425.432 us; speedup vs baseline: 1.3771x; 1.2441x over previous
//
#include <hip/hip_runtime.h>
#include <math.h>

// Problem constants (B=16, S=2048, L=E=512, N=2048)
#define BS_TOK 32768
#define DIM 512
#define NCODE 2048

typedef _Float16 f16x8 __attribute__((ext_vector_type(8)));
typedef _Float16 f16x4 __attribute__((ext_vector_type(4)));
typedef float f32x16 __attribute__((ext_vector_type(16)));

#define LDH 40  // halves per LDS row: 32 data + 8 pad = 80 B

// raw barrier + explicit LDS fence: does NOT drain vmcnt, so prefetch
// global loads stay in flight across the barrier.
#define LGKM0_FENCE asm volatile("s_waitcnt lgkmcnt(0)" ::: "memory")
#define SBAR __builtin_amdgcn_s_barrier()

// ---------------- row L2 normalize + fp16 hi/lo split ----------------
__global__ __launch_bounds__(256) void k_rownorm_split(
    const float* __restrict__ in, _Float16* __restrict__ hi,
    _Float16* __restrict__ lo, int rstride) {
  const int r = blockIdx.x;
  const int t = threadIdx.x;
  const float* row = in + (size_t)r * DIM;
  float v0 = row[t];
  float v1 = row[t + 256];
  float s = v0 * v0 + v1 * v1;
#pragma unroll
  for (int off = 32; off > 0; off >>= 1) s += __shfl_down(s, off, 64);
  __shared__ float ls[4];
  if ((t & 63) == 0) ls[t >> 6] = s;
  __syncthreads();  // also fences: all global reads of this row are done
  float tot = ls[0] + ls[1] + ls[2] + ls[3];
  float sc = 1.0f / fmaxf(sqrtf(tot), 1e-12f);
  float x0 = v0 * sc, x1 = v1 * sc;
  _Float16 h0 = (_Float16)x0;
  _Float16 h1 = (_Float16)x1;
  _Float16 e0 = (_Float16)((x0 - (float)h0) * 2048.0f);
  _Float16 e1 = (_Float16)((x1 - (float)h1) * 2048.0f);
  _Float16* hrow = hi + (size_t)r * rstride;
  _Float16* lrow = lo + (size_t)r * rstride;
  hrow[t] = h0;
  hrow[t + 256] = h1;
  lrow[t] = e0;
  lrow[t + 256] = e1;
}

// ---------------- fp32 -> fp16 hi/lo elementwise split (weights) ------
__global__ __launch_bounds__(256) void k_split_w(const float* __restrict__ w,
                                                 _Float16* __restrict__ hi,
                                                 _Float16* __restrict__ lo) {
  int t = (blockIdx.x * 256 + threadIdx.x) * 4;
  float4 v = *(const float4*)(w + t);
  f16x4 h, l;
  h.x = (_Float16)v.x; l.x = (_Float16)((v.x - (float)h.x) * 2048.0f);
  h.y = (_Float16)v.y; l.y = (_Float16)((v.y - (float)h.y) * 2048.0f);
  h.z = (_Float16)v.z; l.z = (_Float16)((v.z - (float)h.z) * 2048.0f);
  h.w = (_Float16)v.w; l.w = (_Float16)((v.w - (float)h.w) * 2048.0f);
  *(f16x4*)(hi + t) = h;
  *(f16x4*)(lo + t) = l;
}

// ---------------- MFMA split GEMM: input projection -------------------
__global__ __launch_bounds__(256, 2) void k_gemm_mfma_in(
    const float* __restrict__ A, const _Float16* __restrict__ Bhi,
    const _Float16* __restrict__ Blo, const float* __restrict__ bias,
    float* __restrict__ C) {
  __shared__ __align__(16) _Float16 sm[2][4][128 * LDH];  // 81920 B, 2 blk/CU
  const int tid = threadIdx.x;
  const int w = tid >> 6, l = tid & 63;
  const int wm = w >> 1, wn = w & 1;
  const int lm = l & 31, lh = l >> 5;
  const int m0 = blockIdx.y * 128;
  const int n0 = blockIdx.x * 128;
  const int arow = tid >> 3;
  const int ac4 = (tid & 7) << 2;
  const int brow = tid >> 2;
  const int bq = (tid & 3) << 3;

  f32x16 aHH[2][2], aX[2][2];
#pragma unroll
  for (int mb = 0; mb < 2; ++mb)
#pragma unroll
    for (int nb = 0; nb < 2; ++nb) {
      aHH[mb][nb] = (f32x16)0.0f;
      aX[mb][nb] = (f32x16)0.0f;
    }

  float4 ar[4];
  f16x8 brh[2], brl[2];

  auto LOADS = [&](int kt) {
#pragma unroll
    for (int i = 0; i < 4; ++i)
      ar[i] =
          *(const float4*)(A + (size_t)(m0 + arow + 32 * i) * DIM + kt * 32 + ac4);
#pragma unroll
    for (int i = 0; i < 2; ++i) {
      const size_t g = (size_t)(n0 + brow + 64 * i) * DIM + kt * 32 + bq;
      brh[i] = *(const f16x8*)(Bhi + g);
      brl[i] = *(const f16x8*)(Blo + g);
    }
  };
  auto WRITES = [&](int b) {
#pragma unroll
    for (int i = 0; i < 4; ++i) {
      f16x4 h, lo4;
      h.x = (_Float16)ar[i].x; lo4.x = (_Float16)((ar[i].x - (float)h.x) * 2048.0f);
      h.y = (_Float16)ar[i].y; lo4.y = (_Float16)((ar[i].y - (float)h.y) * 2048.0f);
      h.z = (_Float16)ar[i].z; lo4.z = (_Float16)((ar[i].z - (float)h.z) * 2048.0f);
      h.w = (_Float16)ar[i].w; lo4.w = (_Float16)((ar[i].w - (float)h.w) * 2048.0f);
      *(f16x4*)(&sm[b][0][(arow + 32 * i) * LDH + ac4]) = h;
      *(f16x4*)(&sm[b][1][(arow + 32 * i) * LDH + ac4]) = lo4;
    }
#pragma unroll
    for (int i = 0; i < 2; ++i) {
      *(f16x8*)(&sm[b][2][(brow + 64 * i) * LDH + bq]) = brh[i];
      *(f16x8*)(&sm[b][3][(brow + 64 * i) * LDH + bq]) = brl[i];
    }
  };

  LOADS(0);
  WRITES(0);
  LOADS(1);
  LGKM0_FENCE;
  SBAR;
  int cur = 0;
  const int NT = DIM / 32;  // 16
  for (int t = 0; t < NT; ++t) {
    if (t < NT - 1) WRITES(cur ^ 1);
    if (t < NT - 2) LOADS(t + 2);
#pragma unroll
    for (int c = 0; c < 2; ++c) {
      const int ko = c * 16 + lh * 8;
      f16x8 ah[2], al[2], bh[2], bl[2];
#pragma unroll
      for (int mb = 0; mb < 2; ++mb) {
        int r = wm * 64 + mb * 32 + lm;
        ah[mb] = *(const f16x8*)(&sm[cur][0][r * LDH + ko]);
        al[mb] = *(const f16x8*)(&sm[cur][1][r * LDH + ko]);
      }
#pragma unroll
      for (int nb = 0; nb < 2; ++nb) {
        int r = wn * 64 + nb * 32 + lm;
        bh[nb] = *(const f16x8*)(&sm[cur][2][r * LDH + ko]);
        bl[nb] = *(const f16x8*)(&sm[cur][3][r * LDH + ko]);
      }
#pragma unroll
      for (int mb = 0; mb < 2; ++mb)
#pragma unroll
        for (int nb = 0; nb < 2; ++nb) {
          aHH[mb][nb] = __builtin_amdgcn_mfma_f32_32x32x16_f16(
              ah[mb], bh[nb], aHH[mb][nb], 0, 0, 0);
          aX[mb][nb] = __builtin_amdgcn_mfma_f32_32x32x16_f16(
              ah[mb], bl[nb], aX[mb][nb], 0, 0, 0);
          aX[mb][nb] = __builtin_amdgcn_mfma_f32_32x32x16_f16(
              al[mb], bh[nb], aX[mb][nb], 0, 0, 0);
        }
    }
    LGKM0_FENCE;
    SBAR;
    cur ^= 1;
  }
#pragma unroll
  for (int nb = 0; nb < 2; ++nb) {
    int n = n0 + wn * 64 + nb * 32 + lm;
    float bv = bias[n];
#pragma unroll
    for (int mb = 0; mb < 2; ++mb)
#pragma unroll
      for (int r = 0; r < 16; ++r) {
        int m = m0 + wm * 64 + mb * 32 + (r & 3) + 8 * (r >> 2) + 4 * lh;
        C[(size_t)m * DIM + n] =
            aHH[mb][nb][r] + aX[mb][nb][r] * (1.0f / 2048.0f) + bv;
      }
  }
}

// ---------------- MFMA split GEMM: gathered output projection ---------
__global__ __launch_bounds__(256, 2) void k_gemm_mfma_gather(
    const _Float16* __restrict__ Ahi, const _Float16* __restrict__ Alo,
    const _Float16* __restrict__ Bhi, const _Float16* __restrict__ Blo,
    const float* __restrict__ bias, float* __restrict__ C,
    const int* __restrict__ gather, const float* __restrict__ zin) {
  __shared__ __align__(16) _Float16 sm[2][4][128 * LDH];  // 81920 B
  const int tid = threadIdx.x;
  const int w = tid >> 6, l = tid & 63;
  const int wm = w >> 1, wn = w & 1;
  const int lm = l & 31, lh = l >> 5;
  const int m0 = blockIdx.y * 128;
  const int n0 = blockIdx.x * 128;
  const int brow = tid >> 2;
  const int bq = (tid & 3) << 3;
  const size_t g0 = (size_t)gather[m0 + brow] * DIM;
  const size_t g1 = (size_t)gather[m0 + 64 + brow] * DIM;

  f32x16 aHH[2][2], aX[2][2];
#pragma unroll
  for (int mb = 0; mb < 2; ++mb)
#pragma unroll
    for (int nb = 0; nb < 2; ++nb) {
      aHH[mb][nb] = (f32x16)0.0f;
      aX[mb][nb] = (f32x16)0.0f;
    }

  f16x8 arh[2], arl[2], brh[2], brl[2];

  auto LOADS = [&](int kt) {
    const int kc = kt * 32 + bq;
    arh[0] = *(const f16x8*)(Ahi + g0 + kc);
    arl[0] = *(const f16x8*)(Alo + g0 + kc);
    arh[1] = *(const f16x8*)(Ahi + g1 + kc);
    arl[1] = *(const f16x8*)(Alo + g1 + kc);
#pragma unroll
    for (int i = 0; i < 2; ++i) {
      const size_t g = (size_t)(n0 + brow + 64 * i) * DIM + kc;
      brh[i] = *(const f16x8*)(Bhi + g);
      brl[i] = *(const f16x8*)(Blo + g);
    }
  };
  auto WRITES = [&](int b) {
#pragma unroll
    for (int i = 0; i < 2; ++i) {
      *(f16x8*)(&sm[b][0][(brow + 64 * i) * LDH + bq]) = arh[i];
      *(f16x8*)(&sm[b][1][(brow + 64 * i) * LDH + bq]) = arl[i];
      *(f16x8*)(&sm[b][2][(brow + 64 * i) * LDH + bq]) = brh[i];
      *(f16x8*)(&sm[b][3][(brow + 64 * i) * LDH + bq]) = brl[i];
    }
  };

  LOADS(0);
  WRITES(0);
  LOADS(1);
  LGKM0_FENCE;
  SBAR;
  int cur = 0;
  const int NT = DIM / 32;
  for (int t = 0; t < NT; ++t) {
    if (t < NT - 1) WRITES(cur ^ 1);
    if (t < NT - 2) LOADS(t + 2);
#pragma unroll
    for (int c = 0; c < 2; ++c) {
      const int ko = c * 16 + lh * 8;
      f16x8 ah[2], al[2], bh[2], bl[2];
#pragma unroll
      for (int mb = 0; mb < 2; ++mb) {
        int r = wm * 64 + mb * 32 + lm;
        ah[mb] = *(const f16x8*)(&sm[cur][0][r * LDH + ko]);
        al[mb] = *(const f16x8*)(&sm[cur][1][r * LDH + ko]);
      }
#pragma unroll
      for (int nb = 0; nb < 2; ++nb) {
        int r = wn * 64 + nb * 32 + lm;
        bh[nb] = *(const f16x8*)(&sm[cur][2][r * LDH + ko]);
        bl[nb] = *(const f16x8*)(&sm[cur][3][r * LDH + ko]);
      }
#pragma unroll
      for (int mb = 0; mb < 2; ++mb)
#pragma unroll
        for (int nb = 0; nb < 2; ++nb) {
          aHH[mb][nb] = __builtin_amdgcn_mfma_f32_32x32x16_f16(
              ah[mb], bh[nb], aHH[mb][nb], 0, 0, 0);
          aX[mb][nb] = __builtin_amdgcn_mfma_f32_32x32x16_f16(
              ah[mb], bl[nb], aX[mb][nb], 0, 0, 0);
          aX[mb][nb] = __builtin_amdgcn_mfma_f32_32x32x16_f16(
              al[mb], bh[nb], aX[mb][nb], 0, 0, 0);
        }
    }
    LGKM0_FENCE;
    SBAR;
    cur ^= 1;
  }
#pragma unroll
  for (int nb = 0; nb < 2; ++nb) {
    int n = n0 + wn * 64 + nb * 32 + lm;
    float bv = bias[n];
#pragma unroll
    for (int mb = 0; mb < 2; ++mb)
#pragma unroll
      for (int r = 0; r < 16; ++r) {
        int m = m0 + wm * 64 + mb * 32 + (r & 3) + 8 * (r >> 2) + 4 * lh;
        float val = aHH[mb][nb][r] + aX[mb][nb][r] * (1.0f / 2048.0f) + bv;
        float zv = zin[(size_t)m * DIM + n];
        C[(size_t)m * DIM + n] = zv + (val - zv);
      }
  }
}

// ---------------- hi-only MFMA similarity + top-4 candidates ----------
// sim_hh = hi.hi only (1/3 MFMAs, half LDS). Per (token, quarter) the
// kernel emits the top-4 candidates as encoded u32 keys:
//   key = (monotone_fp32(v) & ~0x7FF) | (2047 - n)
// (higher v -> higher key; equal truncated v -> smaller n wins = first-min
// tie-break). k_refine decides exactly. LDS 40960 B -> 4 blocks/CU.
#define SIMK_BM 128
#define SIMK_BN 128
#define NQUART 4
#define QCODES (NCODE / NQUART)  // 512

__global__ __launch_bounds__(256, 4) void k_sim_argmax(
    const _Float16* __restrict__ Apack,  // token rows: 1024 halves = hi|lo
    const _Float16* __restrict__ Bhi, unsigned* __restrict__ cand) {
  __shared__ __align__(16) _Float16 sm[2][2][128 * LDH];  // 40960 B
  float* sC = (float*)sm;  // epilogue alias: [128][65] fp32 = 33280 B

  const int tid = threadIdx.x;
  const int w = tid >> 6, l = tid & 63;
  const int wm = w >> 1, wn = w & 1;
  const int lm = l & 31, lh = l >> 5;
  const int q = blockIdx.x & (NQUART - 1);
  const int tokbase = (blockIdx.x >> 2) * SIMK_BM;
  const int code0 = q * QCODES;
  const int brow = tid >> 2;
  const int bq = (tid & 3) << 3;
  const int t_red = tid >> 1, h_red = tid & 1;

  unsigned e0 = 0, e1 = 0, e2 = 0, e3 = 0;  // top-4 keys, descending

  f16x8 arh[2], brh[2];

  auto LOADS = [&](int nt, int kt) {
    const int kc = kt * 32 + bq;
#pragma unroll
    for (int i = 0; i < 2; ++i) {
      arh[i] =
          *(const f16x8*)(Apack + (size_t)(tokbase + brow + 64 * i) * 1024 + kc);
      brh[i] =
          *(const f16x8*)(Bhi + (size_t)(code0 + nt + brow + 64 * i) * DIM + kc);
    }
  };
  auto WRITES = [&](int b) {
#pragma unroll
    for (int i = 0; i < 2; ++i) {
      *(f16x8*)(&sm[b][0][(brow + 64 * i) * LDH + bq]) = arh[i];
      *(f16x8*)(&sm[b][1][(brow + 64 * i) * LDH + bq]) = brh[i];
    }
  };

  for (int nt = 0; nt < QCODES; nt += SIMK_BN) {
    f32x16 aHH[2][2];
#pragma unroll
    for (int mb = 0; mb < 2; ++mb)
#pragma unroll
      for (int nb = 0; nb < 2; ++nb) aHH[mb][nb] = (f32x16)0.0f;
    __syncthreads();  // prev epilogue's sC reads done before restaging
    LOADS(nt, 0);
    WRITES(0);
    LOADS(nt, 1);
    LGKM0_FENCE;
    SBAR;
    int cur = 0;
    for (int t = 0; t < 16; ++t) {
      if (t < 15) WRITES(cur ^ 1);
      if (t < 14) LOADS(nt, t + 2);
#pragma unroll
      for (int c = 0; c < 2; ++c) {
        const int ko = c * 16 + lh * 8;
        f16x8 ah[2], bh[2];
#pragma unroll
        for (int mb = 0; mb < 2; ++mb)
          ah[mb] = *(const f16x8*)(&sm[cur][0][(wm * 64 + mb * 32 + lm) * LDH + ko]);
#pragma unroll
        for (int nb = 0; nb < 2; ++nb)
          bh[nb] = *(const f16x8*)(&sm[cur][1][(wn * 64 + nb * 32 + lm) * LDH + ko]);
#pragma unroll
        for (int mb = 0; mb < 2; ++mb)
#pragma unroll
          for (int nb = 0; nb < 2; ++nb)
            aHH[mb][nb] = __builtin_amdgcn_mfma_f32_32x32x16_f16(
                ah[mb], bh[nb], aHH[mb][nb], 0, 0, 0);
      }
      LGKM0_FENCE;
      SBAR;
      cur ^= 1;
    }
    // epilogue: two n-halves through LDS; top-4 insertion scan
#pragma unroll
    for (int p = 0; p < 2; ++p) {
      __syncthreads();
      if (wn == p) {
#pragma unroll
        for (int mb = 0; mb < 2; ++mb)
#pragma unroll
          for (int nb = 0; nb < 2; ++nb) {
            int nl = nb * 32 + lm;
#pragma unroll
            for (int r = 0; r < 16; ++r) {
              int m = wm * 64 + mb * 32 + (r & 3) + 8 * (r >> 2) + 4 * lh;
              sC[m * 65 + nl] = aHH[mb][nb][r];
            }
          }
      }
      __syncthreads();
      const float* rowp = &sC[t_red * 65 + h_red * 32];
      const int ncomp = 2047 - (code0 + nt + p * 64 + h_red * 32);
#pragma unroll
      for (int i = 0; i < 32; ++i) {
        float v = rowp[i];
        unsigned s = __float_as_uint(v);
        s = (s & 0x80000000u) ? ~s : (s | 0x80000000u);
        unsigned key = (s & 0xFFFFF800u) | (unsigned)(ncomp - i);
        if (key > e3) {  // rare after warm-up
          unsigned y = key, t2;
          t2 = e0 > y ? e0 : y; y = e0 > y ? y : e0; e0 = t2;
          t2 = e1 > y ? e1 : y; y = e1 > y ? y : e1; e1 = t2;
          t2 = e2 > y ? e2 : y; y = e2 > y ? y : e2; e2 = t2;
          e3 = e3 > y ? e3 : y;
        }
      }
    }
  }
  // merge the two half-lane lists (partition of this quarter's codes)
  unsigned o0 = __shfl_xor(e0, 1), o1 = __shfl_xor(e1, 1),
           o2 = __shfl_xor(e2, 1), o3 = __shfl_xor(e3, 1);
#define INS4(x)                                    \
  {                                                \
    unsigned y = (x), t2;                          \
    t2 = e0 > y ? e0 : y; y = e0 > y ? y : e0; e0 = t2; \
    t2 = e1 > y ? e1 : y; y = e1 > y ? y : e1; e1 = t2; \
    t2 = e2 > y ? e2 : y; y = e2 > y ? y : e2; e2 = t2; \
    e3 = e3 > y ? e3 : y;                          \
  }
  INS4(o0) INS4(o1) INS4(o2) INS4(o3)
  if (h_red == 0) {
    unsigned* cp = cand + ((size_t)(tokbase + t_red) * NQUART + q) * 4;
    cp[0] = e0; cp[1] = e1; cp[2] = e2; cp[3] = e3;
  }
}

// ---------------- exact refine over 16 candidates per token -----------
// Unflagged (margin >= THETA): hi-only argmax is provably safe
// (worst-case |err| <= 2^-10 each side). Flagged: recompute exact fp32
// sims (hi + lo/2048 reconstruction) for all 16 candidates.
#define THETA 2.125e-3f

__global__ __launch_bounds__(256) void k_refine(
    const unsigned* __restrict__ cand, const _Float16* __restrict__ zf16,
    const _Float16* __restrict__ embhi, const _Float16* __restrict__ emblo,
    int* __restrict__ idx, float* __restrict__ idxf) {
  const int tok = (blockIdx.x << 2) + (threadIdx.x >> 6);
  const int lane = threadIdx.x & 63;
  unsigned k32 = (lane < 16) ? cand[(size_t)tok * 16 + lane] : 0u;
  // wave-wide top-2 of the 16 keys (lanes >=16 contribute 0 < any real key)
  unsigned m1 = k32, m2 = 0;
#pragma unroll
  for (int off = 1; off < 64; off <<= 1) {
    unsigned q1 = __shfl_xor(m1, off), q2 = __shfl_xor(m2, off);
    unsigned hi = m1 > q1 ? m1 : q1;
    unsigned lo = m1 > q1 ? q1 : m1;
    unsigned s2 = m2 > q2 ? m2 : q2;
    m2 = lo > s2 ? lo : s2;
    m1 = hi;
  }
  // decode truncated values (error <= ~3e-5, absorbed by THETA)
  unsigned s1 = m1 & 0xFFFFF800u, s2e = m2 & 0xFFFFF800u;
  float v1 = __uint_as_float((s1 & 0x80000000u) ? (s1 & 0x7FFFFFFFu) : ~s1);
  float v2 = __uint_as_float((s2e & 0x80000000u) ? (s2e & 0x7FFFFFFFu) : ~s2e);
  if (v1 - v2 >= THETA) {
    if (lane == 0) {
      int n1 = 2047 - (int)(m1 & 0x7FFu);
      idx[tok] = n1;
      idxf[tok] = (float)n1;
    }
    return;
  }
  // exact path: lane -> (candidate c = lane&15, dim segment seg = lane>>4)
  const int c = lane & 15, seg = lane >> 4;
  unsigned ck = __shfl(k32, c);
  int n = 2047 - (int)(ck & 0x7FFu);
  const _Float16* zh = zf16 + (size_t)tok * 1024 + seg * 128;
  const _Float16* eh = embhi + (size_t)n * DIM + seg * 128;
  const _Float16* el = emblo + (size_t)n * DIM + seg * 128;
  float s = 0.0f;
#pragma unroll
  for (int d = 0; d < 128; d += 8) {
    f16x8 a = *(const f16x8*)(zh + d);
    f16x8 b = *(const f16x8*)(zh + 512 + d);
    f16x8 e = *(const f16x8*)(eh + d);
    f16x8 f = *(const f16x8*)(el + d);
#pragma unroll
    for (int j = 0; j < 8; ++j)
      s += ((float)a[j] + (float)b[j] * (1.0f / 2048.0f)) *
           ((float)e[j] + (float)f[j] * (1.0f / 2048.0f));
  }
  s += __shfl_xor(s, 16);
  s += __shfl_xor(s, 32);
  unsigned sb = __float_as_uint(s);
  sb = (sb & 0x80000000u) ? ~sb : (sb | 0x80000000u);
  unsigned long long kk =
      ((unsigned long long)sb << 32) | (unsigned)(2047 - n);
  if (lane >= 16) kk = 0ull;
#pragma unroll
  for (int off = 1; off < 16; off <<= 1) {
    unsigned long long o = __shfl_xor(kk, off);
    kk = o > kk ? o : kk;
  }
  if (lane == 0) {
    int nb = 2047 - (int)((unsigned)kk & 0x7FFu);
    idx[tok] = nb;
    idxf[tok] = (float)nb;
  }
}

extern "C" void kernel_launch(void* const* d_in, const int* in_sizes, int n_in,
                              void* d_out, int out_size, void* d_ws,
                              size_t ws_size, hipStream_t stream) {
  const float* z = (const float*)d_in[0];
  // d_in[1] = mask, unused
  const float* W_in = (const float*)d_in[2];
  const float* b_in = (const float*)d_in[3];
  const float* W_out = (const float*)d_in[4];
  const float* b_out = (const float*)d_in[5];
  const float* emb = (const float*)d_in[6];

  float* out = (float*)d_out;
  float* zq = out;                           // 32768*512 fp32 (final output)
  float* idxf = out + (size_t)BS_TOK * DIM;  // 32768 fp32 indices

  // ws layout (~8.1 MB): embhi|emblo|winhi|winlo|wouthi|woutlo|cand|idx
  _Float16* embhi = (_Float16*)d_ws;
  _Float16* emblo = embhi + (size_t)NCODE * DIM;
  _Float16* winhi = emblo + (size_t)NCODE * DIM;
  _Float16* winlo = winhi + (size_t)DIM * DIM;
  _Float16* wouthi = winlo + (size_t)DIM * DIM;
  _Float16* woutlo = wouthi + (size_t)DIM * DIM;
  unsigned* cand = (unsigned*)(woutlo + (size_t)DIM * DIM);  // 32768*16 u32
  int* idx = (int*)(cand + (size_t)BS_TOK * 16);

  // zf fp32 lives in the zq region; then packed in-place to fp16 hi|lo rows
  float* zf = zq;
  _Float16* zf16 = (_Float16*)zf;  // row stride 1024 halves: [hi 512|lo 512]

  // 0) split weights
  k_split_w<<<DIM * DIM / 1024, 256, 0, stream>>>(W_in, winhi, winlo);
  k_split_w<<<DIM * DIM / 1024, 256, 0, stream>>>(W_out, wouthi, woutlo);
  // 1) normalize + split codebook rows -> ws
  k_rownorm_split<<<NCODE, 256, 0, stream>>>(emb, embhi, emblo, DIM);
  // 2) zf = z @ W_in^T + b_in (MFMA fp16-split, A converted on the fly)
  k_gemm_mfma_in<<<dim3(DIM / 128, BS_TOK / 128), 256, 0, stream>>>(
      z, winhi, winlo, b_in, zf);
  // 3) normalize zf rows, split to fp16 hi/lo IN-PLACE (packed rows)
  k_rownorm_split<<<BS_TOK, 256, 0, stream>>>(zf, zf16, zf16 + 512, 1024);
  // 4) hi-only MFMA similarity -> top-4 candidates per (token, quarter)
  k_sim_argmax<<<(BS_TOK / SIMK_BM) * NQUART, 256, 0, stream>>>(zf16, embhi,
                                                                cand);
  // 5) exact refine -> idx (ws) + idxf (d_out)
  k_refine<<<BS_TOK / 4, 256, 0, stream>>>(cand, zf16, embhi, emblo, idx,
                                           idxf);
  // 6) zq = emb_n[idx] @ W_out^T + b_out (+ straight-through), overwrites zf
  k_gemm_mfma_gather<<<dim3(DIM / 128, BS_TOK / 128), 256, 0, stream>>>(
      embhi, emblo, wouthi, woutlo, b_out, zq, idx, z);
}

// Round 6
// 392.511 us; speedup vs baseline: 1.4926x; 1.0839x over previous
//
#include <hip/hip_runtime.h>
#include <math.h>

// Problem constants (B=16, S=2048, L=E=512, N=2048)
#define BS_TOK 32768
#define DIM 512
#define NCODE 2048

typedef _Float16 f16x8 __attribute__((ext_vector_type(8)));
typedef _Float16 f16x4 __attribute__((ext_vector_type(4)));
typedef float f32x16 __attribute__((ext_vector_type(16)));

#define LDH 40  // halves per LDS row: 32 data + 8 pad = 80 B

// raw barrier + explicit LDS fence: does NOT drain vmcnt, so prefetch
// global loads stay in flight across the barrier.
#define LGKM0_FENCE asm volatile("s_waitcnt lgkmcnt(0)" ::: "memory")
#define SBAR __builtin_amdgcn_s_barrier()

// ---------------- row L2 normalize + fp16 hi/lo split (codebook) -----
__global__ __launch_bounds__(256) void k_rownorm_split(
    const float* __restrict__ in, _Float16* __restrict__ hi,
    _Float16* __restrict__ lo, int rstride) {
  const int r = blockIdx.x;
  const int t = threadIdx.x;
  const float* row = in + (size_t)r * DIM;
  float v0 = row[t];
  float v1 = row[t + 256];
  float s = v0 * v0 + v1 * v1;
#pragma unroll
  for (int off = 32; off > 0; off >>= 1) s += __shfl_down(s, off, 64);
  __shared__ float ls[4];
  if ((t & 63) == 0) ls[t >> 6] = s;
  __syncthreads();
  float tot = ls[0] + ls[1] + ls[2] + ls[3];
  float sc = 1.0f / fmaxf(sqrtf(tot), 1e-12f);
  float x0 = v0 * sc, x1 = v1 * sc;
  _Float16 h0 = (_Float16)x0;
  _Float16 h1 = (_Float16)x1;
  _Float16 e0 = (_Float16)((x0 - (float)h0) * 2048.0f);
  _Float16 e1 = (_Float16)((x1 - (float)h1) * 2048.0f);
  _Float16* hrow = hi + (size_t)r * rstride;
  _Float16* lrow = lo + (size_t)r * rstride;
  hrow[t] = h0;
  hrow[t + 256] = h1;
  lrow[t] = e0;
  lrow[t + 256] = e1;
}

// ---------------- fp32 -> fp16 hi/lo elementwise split (weights) ------
__global__ __launch_bounds__(256) void k_split_w(const float* __restrict__ w,
                                                 _Float16* __restrict__ hi,
                                                 _Float16* __restrict__ lo) {
  int t = (blockIdx.x * 256 + threadIdx.x) * 4;
  float4 v = *(const float4*)(w + t);
  f16x4 h, l;
  h.x = (_Float16)v.x; l.x = (_Float16)((v.x - (float)h.x) * 2048.0f);
  h.y = (_Float16)v.y; l.y = (_Float16)((v.y - (float)h.y) * 2048.0f);
  h.z = (_Float16)v.z; l.z = (_Float16)((v.z - (float)h.z) * 2048.0f);
  h.w = (_Float16)v.w; l.w = (_Float16)((v.w - (float)h.w) * 2048.0f);
  *(f16x4*)(hi + t) = h;
  *(f16x4*)(lo + t) = l;
}

// ---------------- MFMA split GEMM: input projection -------------------
// Epilogue FUSED: writes zf16 packed rows [hi 512 | lo 512] directly
// (no normalization — argmax over codes is scale-invariant in zf).
__global__ __launch_bounds__(256, 2) void k_gemm_mfma_in(
    const float* __restrict__ A, const _Float16* __restrict__ Bhi,
    const _Float16* __restrict__ Blo, const float* __restrict__ bias,
    _Float16* __restrict__ zf16) {
  __shared__ __align__(16) _Float16 sm[2][4][128 * LDH];  // 81920 B, 2 blk/CU
  const int tid = threadIdx.x;
  const int w = tid >> 6, l = tid & 63;
  const int wm = w >> 1, wn = w & 1;
  const int lm = l & 31, lh = l >> 5;
  const int m0 = blockIdx.y * 128;
  const int n0 = blockIdx.x * 128;
  const int arow = tid >> 3;
  const int ac4 = (tid & 7) << 2;
  const int brow = tid >> 2;
  const int bq = (tid & 3) << 3;

  f32x16 aHH[2][2], aX[2][2];
#pragma unroll
  for (int mb = 0; mb < 2; ++mb)
#pragma unroll
    for (int nb = 0; nb < 2; ++nb) {
      aHH[mb][nb] = (f32x16)0.0f;
      aX[mb][nb] = (f32x16)0.0f;
    }

  float4 ar[4];
  f16x8 brh[2], brl[2];

  auto LOADS = [&](int kt) {
#pragma unroll
    for (int i = 0; i < 4; ++i)
      ar[i] =
          *(const float4*)(A + (size_t)(m0 + arow + 32 * i) * DIM + kt * 32 + ac4);
#pragma unroll
    for (int i = 0; i < 2; ++i) {
      const size_t g = (size_t)(n0 + brow + 64 * i) * DIM + kt * 32 + bq;
      brh[i] = *(const f16x8*)(Bhi + g);
      brl[i] = *(const f16x8*)(Blo + g);
    }
  };
  auto WRITES = [&](int b) {
#pragma unroll
    for (int i = 0; i < 4; ++i) {
      f16x4 h, lo4;
      h.x = (_Float16)ar[i].x; lo4.x = (_Float16)((ar[i].x - (float)h.x) * 2048.0f);
      h.y = (_Float16)ar[i].y; lo4.y = (_Float16)((ar[i].y - (float)h.y) * 2048.0f);
      h.z = (_Float16)ar[i].z; lo4.z = (_Float16)((ar[i].z - (float)h.z) * 2048.0f);
      h.w = (_Float16)ar[i].w; lo4.w = (_Float16)((ar[i].w - (float)h.w) * 2048.0f);
      *(f16x4*)(&sm[b][0][(arow + 32 * i) * LDH + ac4]) = h;
      *(f16x4*)(&sm[b][1][(arow + 32 * i) * LDH + ac4]) = lo4;
    }
#pragma unroll
    for (int i = 0; i < 2; ++i) {
      *(f16x8*)(&sm[b][2][(brow + 64 * i) * LDH + bq]) = brh[i];
      *(f16x8*)(&sm[b][3][(brow + 64 * i) * LDH + bq]) = brl[i];
    }
  };

  LOADS(0);
  WRITES(0);
  LOADS(1);
  LGKM0_FENCE;
  SBAR;
  int cur = 0;
  const int NT = DIM / 32;  // 16
  for (int t = 0; t < NT; ++t) {
    if (t < NT - 1) WRITES(cur ^ 1);
    if (t < NT - 2) LOADS(t + 2);
#pragma unroll
    for (int c = 0; c < 2; ++c) {
      const int ko = c * 16 + lh * 8;
      f16x8 ah[2], al[2], bh[2], bl[2];
#pragma unroll
      for (int mb = 0; mb < 2; ++mb) {
        int r = wm * 64 + mb * 32 + lm;
        ah[mb] = *(const f16x8*)(&sm[cur][0][r * LDH + ko]);
        al[mb] = *(const f16x8*)(&sm[cur][1][r * LDH + ko]);
      }
#pragma unroll
      for (int nb = 0; nb < 2; ++nb) {
        int r = wn * 64 + nb * 32 + lm;
        bh[nb] = *(const f16x8*)(&sm[cur][2][r * LDH + ko]);
        bl[nb] = *(const f16x8*)(&sm[cur][3][r * LDH + ko]);
      }
#pragma unroll
      for (int mb = 0; mb < 2; ++mb)
#pragma unroll
        for (int nb = 0; nb < 2; ++nb) {
          aHH[mb][nb] = __builtin_amdgcn_mfma_f32_32x32x16_f16(
              ah[mb], bh[nb], aHH[mb][nb], 0, 0, 0);
          aX[mb][nb] = __builtin_amdgcn_mfma_f32_32x32x16_f16(
              ah[mb], bl[nb], aX[mb][nb], 0, 0, 0);
          aX[mb][nb] = __builtin_amdgcn_mfma_f32_32x32x16_f16(
              al[mb], bh[nb], aX[mb][nb], 0, 0, 0);
        }
    }
    LGKM0_FENCE;
    SBAR;
    cur ^= 1;
  }
#pragma unroll
  for (int nb = 0; nb < 2; ++nb) {
    int n = n0 + wn * 64 + nb * 32 + lm;
    float bv = bias[n];
#pragma unroll
    for (int mb = 0; mb < 2; ++mb)
#pragma unroll
      for (int r = 0; r < 16; ++r) {
        int m = m0 + wm * 64 + mb * 32 + (r & 3) + 8 * (r >> 2) + 4 * lh;
        float val = aHH[mb][nb][r] + aX[mb][nb][r] * (1.0f / 2048.0f) + bv;
        _Float16 h = (_Float16)val;
        _Float16 lo = (_Float16)((val - (float)h) * 2048.0f);
        zf16[(size_t)m * 1024 + n] = h;
        zf16[(size_t)m * 1024 + 512 + n] = lo;
      }
  }
}

// ---------------- MFMA split GEMM: codebook output table --------------
// table[c,:] = emb_n[c] @ W_out^T + b_out for ALL 2048 codes (1/16 the
// FLOPs of the per-token gather GEMM; gather commutes with linear map).
__global__ __launch_bounds__(256, 2) void k_gemm_codebook(
    const _Float16* __restrict__ Ahi, const _Float16* __restrict__ Alo,
    const _Float16* __restrict__ Bhi, const _Float16* __restrict__ Blo,
    const float* __restrict__ bias, float* __restrict__ table) {
  __shared__ __align__(16) _Float16 sm[2][4][128 * LDH];  // 81920 B
  const int tid = threadIdx.x;
  const int w = tid >> 6, l = tid & 63;
  const int wm = w >> 1, wn = w & 1;
  const int lm = l & 31, lh = l >> 5;
  const int m0 = blockIdx.y * 128;
  const int n0 = blockIdx.x * 128;
  const int brow = tid >> 2;
  const int bq = (tid & 3) << 3;

  f32x16 aHH[2][2], aX[2][2];
#pragma unroll
  for (int mb = 0; mb < 2; ++mb)
#pragma unroll
    for (int nb = 0; nb < 2; ++nb) {
      aHH[mb][nb] = (f32x16)0.0f;
      aX[mb][nb] = (f32x16)0.0f;
    }

  f16x8 arh[2], arl[2], brh[2], brl[2];

  auto LOADS = [&](int kt) {
    const int kc = kt * 32 + bq;
#pragma unroll
    for (int i = 0; i < 2; ++i) {
      const size_t ga = (size_t)(m0 + brow + 64 * i) * DIM + kc;
      arh[i] = *(const f16x8*)(Ahi + ga);
      arl[i] = *(const f16x8*)(Alo + ga);
      const size_t g = (size_t)(n0 + brow + 64 * i) * DIM + kc;
      brh[i] = *(const f16x8*)(Bhi + g);
      brl[i] = *(const f16x8*)(Blo + g);
    }
  };
  auto WRITES = [&](int b) {
#pragma unroll
    for (int i = 0; i < 2; ++i) {
      *(f16x8*)(&sm[b][0][(brow + 64 * i) * LDH + bq]) = arh[i];
      *(f16x8*)(&sm[b][1][(brow + 64 * i) * LDH + bq]) = arl[i];
      *(f16x8*)(&sm[b][2][(brow + 64 * i) * LDH + bq]) = brh[i];
      *(f16x8*)(&sm[b][3][(brow + 64 * i) * LDH + bq]) = brl[i];
    }
  };

  LOADS(0);
  WRITES(0);
  LOADS(1);
  LGKM0_FENCE;
  SBAR;
  int cur = 0;
  const int NT = DIM / 32;
  for (int t = 0; t < NT; ++t) {
    if (t < NT - 1) WRITES(cur ^ 1);
    if (t < NT - 2) LOADS(t + 2);
#pragma unroll
    for (int c = 0; c < 2; ++c) {
      const int ko = c * 16 + lh * 8;
      f16x8 ah[2], al[2], bh[2], bl[2];
#pragma unroll
      for (int mb = 0; mb < 2; ++mb) {
        int r = wm * 64 + mb * 32 + lm;
        ah[mb] = *(const f16x8*)(&sm[cur][0][r * LDH + ko]);
        al[mb] = *(const f16x8*)(&sm[cur][1][r * LDH + ko]);
      }
#pragma unroll
      for (int nb = 0; nb < 2; ++nb) {
        int r = wn * 64 + nb * 32 + lm;
        bh[nb] = *(const f16x8*)(&sm[cur][2][r * LDH + ko]);
        bl[nb] = *(const f16x8*)(&sm[cur][3][r * LDH + ko]);
      }
#pragma unroll
      for (int mb = 0; mb < 2; ++mb)
#pragma unroll
        for (int nb = 0; nb < 2; ++nb) {
          aHH[mb][nb] = __builtin_amdgcn_mfma_f32_32x32x16_f16(
              ah[mb], bh[nb], aHH[mb][nb], 0, 0, 0);
          aX[mb][nb] = __builtin_amdgcn_mfma_f32_32x32x16_f16(
              ah[mb], bl[nb], aX[mb][nb], 0, 0, 0);
          aX[mb][nb] = __builtin_amdgcn_mfma_f32_32x32x16_f16(
              al[mb], bh[nb], aX[mb][nb], 0, 0, 0);
        }
    }
    LGKM0_FENCE;
    SBAR;
    cur ^= 1;
  }
#pragma unroll
  for (int nb = 0; nb < 2; ++nb) {
    int n = n0 + wn * 64 + nb * 32 + lm;
    float bv = bias[n];
#pragma unroll
    for (int mb = 0; mb < 2; ++mb)
#pragma unroll
      for (int r = 0; r < 16; ++r) {
        int m = m0 + wm * 64 + mb * 32 + (r & 3) + 8 * (r >> 2) + 4 * lh;
        table[(size_t)m * DIM + n] =
            aHH[mb][nb][r] + aX[mb][nb][r] * (1.0f / 2048.0f) + bv;
      }
  }
}

// ---------------- gather + straight-through copy ----------------------
// zq[m,:] = z[m,:] + (table[idx[m],:] - z[m,:])   (strict fp32, as ref)
__global__ __launch_bounds__(256) void k_gather_st(
    const float* __restrict__ z, const float* __restrict__ table,
    const int* __restrict__ idx, float* __restrict__ out) {
  int g = blockIdx.x * 256 + threadIdx.x;  // one float4 per thread
  int m = g >> 7;
  int c = (g & 127) << 2;
  int n = idx[m];
  float4 t = *(const float4*)(table + (size_t)n * DIM + c);
  float4 zv = *(const float4*)(z + (size_t)m * DIM + c);
  float4 o;
  o.x = zv.x + (t.x - zv.x);
  o.y = zv.y + (t.y - zv.y);
  o.z = zv.z + (t.z - zv.z);
  o.w = zv.w + (t.w - zv.w);
  *(float4*)(out + (size_t)m * DIM + c) = o;
}

// ---------------- hi-only MFMA similarity + top-4 candidates ----------
// A rows are UNNORMALIZED zf (argmax is scale-invariant). Keys:
//   key = (monotone_fp32(v) & ~0x7FF) | (2047 - n)
// k_refine decides exactly with a ||zf||-scaled margin. 4 blocks/CU.
#define SIMK_BM 128
#define SIMK_BN 128
#define NQUART 4
#define QCODES (NCODE / NQUART)  // 512

__global__ __launch_bounds__(256, 4) void k_sim_argmax(
    const _Float16* __restrict__ Apack,  // token rows: 1024 halves = hi|lo
    const _Float16* __restrict__ Bhi, unsigned* __restrict__ cand) {
  __shared__ __align__(16) _Float16 sm[2][2][128 * LDH];  // 40960 B
  float* sC = (float*)sm;  // epilogue alias: [128][65] fp32 = 33280 B

  const int tid = threadIdx.x;
  const int w = tid >> 6, l = tid & 63;
  const int wm = w >> 1, wn = w & 1;
  const int lm = l & 31, lh = l >> 5;
  const int q = blockIdx.x & (NQUART - 1);
  const int tokbase = (blockIdx.x >> 2) * SIMK_BM;
  const int code0 = q * QCODES;
  const int brow = tid >> 2;
  const int bq = (tid & 3) << 3;
  const int t_red = tid >> 1, h_red = tid & 1;

  unsigned e0 = 0, e1 = 0, e2 = 0, e3 = 0;  // top-4 keys, descending

  f16x8 arh[2], brh[2];

  auto LOADS = [&](int nt, int kt) {
    const int kc = kt * 32 + bq;
#pragma unroll
    for (int i = 0; i < 2; ++i) {
      arh[i] =
          *(const f16x8*)(Apack + (size_t)(tokbase + brow + 64 * i) * 1024 + kc);
      brh[i] =
          *(const f16x8*)(Bhi + (size_t)(code0 + nt + brow + 64 * i) * DIM + kc);
    }
  };
  auto WRITES = [&](int b) {
#pragma unroll
    for (int i = 0; i < 2; ++i) {
      *(f16x8*)(&sm[b][0][(brow + 64 * i) * LDH + bq]) = arh[i];
      *(f16x8*)(&sm[b][1][(brow + 64 * i) * LDH + bq]) = brh[i];
    }
  };

  for (int nt = 0; nt < QCODES; nt += SIMK_BN) {
    f32x16 aHH[2][2];
#pragma unroll
    for (int mb = 0; mb < 2; ++mb)
#pragma unroll
      for (int nb = 0; nb < 2; ++nb) aHH[mb][nb] = (f32x16)0.0f;
    __syncthreads();  // prev epilogue's sC reads done before restaging
    LOADS(nt, 0);
    WRITES(0);
    LOADS(nt, 1);
    LGKM0_FENCE;
    SBAR;
    int cur = 0;
    for (int t = 0; t < 16; ++t) {
      if (t < 15) WRITES(cur ^ 1);
      if (t < 14) LOADS(nt, t + 2);
#pragma unroll
      for (int c = 0; c < 2; ++c) {
        const int ko = c * 16 + lh * 8;
        f16x8 ah[2], bh[2];
#pragma unroll
        for (int mb = 0; mb < 2; ++mb)
          ah[mb] = *(const f16x8*)(&sm[cur][0][(wm * 64 + mb * 32 + lm) * LDH + ko]);
#pragma unroll
        for (int nb = 0; nb < 2; ++nb)
          bh[nb] = *(const f16x8*)(&sm[cur][1][(wn * 64 + nb * 32 + lm) * LDH + ko]);
#pragma unroll
        for (int mb = 0; mb < 2; ++mb)
#pragma unroll
          for (int nb = 0; nb < 2; ++nb)
            aHH[mb][nb] = __builtin_amdgcn_mfma_f32_32x32x16_f16(
                ah[mb], bh[nb], aHH[mb][nb], 0, 0, 0);
      }
      LGKM0_FENCE;
      SBAR;
      cur ^= 1;
    }
    // epilogue: two n-halves through LDS; top-4 insertion scan
#pragma unroll
    for (int p = 0; p < 2; ++p) {
      __syncthreads();
      if (wn == p) {
#pragma unroll
        for (int mb = 0; mb < 2; ++mb)
#pragma unroll
          for (int nb = 0; nb < 2; ++nb) {
            int nl = nb * 32 + lm;
#pragma unroll
            for (int r = 0; r < 16; ++r) {
              int m = wm * 64 + mb * 32 + (r & 3) + 8 * (r >> 2) + 4 * lh;
              sC[m * 65 + nl] = aHH[mb][nb][r];
            }
          }
      }
      __syncthreads();
      const float* rowp = &sC[t_red * 65 + h_red * 32];
      const int ncomp = 2047 - (code0 + nt + p * 64 + h_red * 32);
#pragma unroll
      for (int i = 0; i < 32; ++i) {
        float v = rowp[i];
        unsigned s = __float_as_uint(v);
        s = (s & 0x80000000u) ? ~s : (s | 0x80000000u);
        unsigned key = (s & 0xFFFFF800u) | (unsigned)(ncomp - i);
        if (key > e3) {  // rare after warm-up
          unsigned y = key, t2;
          t2 = e0 > y ? e0 : y; y = e0 > y ? y : e0; e0 = t2;
          t2 = e1 > y ? e1 : y; y = e1 > y ? y : e1; e1 = t2;
          t2 = e2 > y ? e2 : y; y = e2 > y ? y : e2; e2 = t2;
          e3 = e3 > y ? e3 : y;
        }
      }
    }
  }
  // merge the two half-lane lists (partition of this quarter's codes)
  unsigned o0 = __shfl_xor(e0, 1), o1 = __shfl_xor(e1, 1),
           o2 = __shfl_xor(e2, 1), o3 = __shfl_xor(e3, 1);
#define INS4(x)                                    \
  {                                                \
    unsigned y = (x), t2;                          \
    t2 = e0 > y ? e0 : y; y = e0 > y ? y : e0; e0 = t2; \
    t2 = e1 > y ? e1 : y; y = e1 > y ? y : e1; e1 = t2; \
    t2 = e2 > y ? e2 : y; y = e2 > y ? y : e2; e2 = t2; \
    e3 = e3 > y ? e3 : y;                          \
  }
  INS4(o0) INS4(o1) INS4(o2) INS4(o3)
  if (h_red == 0) {
    unsigned* cp = cand + ((size_t)(tokbase + t_red) * NQUART + q) * 4;
    cp[0] = e0; cp[1] = e1; cp[2] = e2; cp[3] = e3;
  }
}

// ---------------- exact refine over 16 candidates per token -----------
// Margin test scaled by ||zf_hi|| (zf is unnormalized):
//   split error per sim <= 2^-10 * ||zf||;  key truncation <= 2^-11*|v|.
//   THETA = 2.0e-3*||zf_hi|| + 2^-10*(|v1|+|v2|) + slop.
__global__ __launch_bounds__(256) void k_refine(
    const unsigned* __restrict__ cand, const _Float16* __restrict__ zf16,
    const _Float16* __restrict__ embhi, const _Float16* __restrict__ emblo,
    int* __restrict__ idx, float* __restrict__ idxf) {
  const int tok = (blockIdx.x << 2) + (threadIdx.x >> 6);
  const int lane = threadIdx.x & 63;
  // ||zf_hi||^2 across the wave (also warms cache for exact path)
  f16x8 zh8 = *(const f16x8*)(zf16 + (size_t)tok * 1024 + lane * 8);
  float ss = 0.0f;
#pragma unroll
  for (int j = 0; j < 8; ++j) {
    float x = (float)zh8[j];
    ss += x * x;
  }
#pragma unroll
  for (int off = 1; off < 64; off <<= 1) ss += __shfl_xor(ss, off);

  unsigned k32 = (lane < 16) ? cand[(size_t)tok * 16 + lane] : 0u;
  // wave-wide top-2 of the 16 keys
  unsigned m1 = k32, m2 = 0;
#pragma unroll
  for (int off = 1; off < 64; off <<= 1) {
    unsigned q1 = __shfl_xor(m1, off), q2 = __shfl_xor(m2, off);
    unsigned hi = m1 > q1 ? m1 : q1;
    unsigned lo = m1 > q1 ? q1 : m1;
    unsigned s2 = m2 > q2 ? m2 : q2;
    m2 = lo > s2 ? lo : s2;
    m1 = hi;
  }
  unsigned s1 = m1 & 0xFFFFF800u, s2e = m2 & 0xFFFFF800u;
  float v1 = __uint_as_float((s1 & 0x80000000u) ? (s1 & 0x7FFFFFFFu) : ~s1);
  float v2 = __uint_as_float((s2e & 0x80000000u) ? (s2e & 0x7FFFFFFFu) : ~s2e);
  float theta = 2.0e-3f * sqrtf(ss) +
                9.765625e-4f * (fabsf(v1) + fabsf(v2)) + 1e-6f;
  if (v1 - v2 >= theta) {
    if (lane == 0) {
      int n1 = 2047 - (int)(m1 & 0x7FFu);
      idx[tok] = n1;
      idxf[tok] = (float)n1;
    }
    return;
  }
  // exact path: lane -> (candidate c = lane&15, dim segment seg = lane>>4)
  const int c = lane & 15, seg = lane >> 4;
  unsigned ck = __shfl(k32, c);
  int n = 2047 - (int)(ck & 0x7FFu);
  const _Float16* zh = zf16 + (size_t)tok * 1024 + seg * 128;
  const _Float16* eh = embhi + (size_t)n * DIM + seg * 128;
  const _Float16* el = emblo + (size_t)n * DIM + seg * 128;
  float s = 0.0f;
#pragma unroll
  for (int d = 0; d < 128; d += 8) {
    f16x8 a = *(const f16x8*)(zh + d);
    f16x8 b = *(const f16x8*)(zh + 512 + d);
    f16x8 e = *(const f16x8*)(eh + d);
    f16x8 f = *(const f16x8*)(el + d);
#pragma unroll
    for (int j = 0; j < 8; ++j)
      s += ((float)a[j] + (float)b[j] * (1.0f / 2048.0f)) *
           ((float)e[j] + (float)f[j] * (1.0f / 2048.0f));
  }
  s += __shfl_xor(s, 16);
  s += __shfl_xor(s, 32);
  unsigned sb = __float_as_uint(s);
  sb = (sb & 0x80000000u) ? ~sb : (sb | 0x80000000u);
  unsigned long long kk =
      ((unsigned long long)sb << 32) | (unsigned)(2047 - n);
  if (lane >= 16) kk = 0ull;
#pragma unroll
  for (int off = 1; off < 16; off <<= 1) {
    unsigned long long o = __shfl_xor(kk, off);
    kk = o > kk ? o : kk;
  }
  if (lane == 0) {
    int nb = 2047 - (int)((unsigned)kk & 0x7FFu);
    idx[tok] = nb;
    idxf[tok] = (float)nb;
  }
}

extern "C" void kernel_launch(void* const* d_in, const int* in_sizes, int n_in,
                              void* d_out, int out_size, void* d_ws,
                              size_t ws_size, hipStream_t stream) {
  const float* z = (const float*)d_in[0];
  // d_in[1] = mask, unused
  const float* W_in = (const float*)d_in[2];
  const float* b_in = (const float*)d_in[3];
  const float* W_out = (const float*)d_in[4];
  const float* b_out = (const float*)d_in[5];
  const float* emb = (const float*)d_in[6];

  float* out = (float*)d_out;
  float* zq = out;                           // 32768*512 fp32 (final output)
  float* idxf = out + (size_t)BS_TOK * DIM;  // 32768 fp32 indices

  // ws layout (10.125 MB): embhi|emblo|winhi|winlo|wouthi|woutlo|idx|scratch
  // scratch holds cand (2 MB, dead after refine) then table (4 MB) overlaid.
  _Float16* embhi = (_Float16*)d_ws;
  _Float16* emblo = embhi + (size_t)NCODE * DIM;
  _Float16* winhi = emblo + (size_t)NCODE * DIM;
  _Float16* winlo = winhi + (size_t)DIM * DIM;
  _Float16* wouthi = winlo + (size_t)DIM * DIM;
  _Float16* woutlo = wouthi + (size_t)DIM * DIM;
  int* idx = (int*)(woutlo + (size_t)DIM * DIM);
  unsigned* cand = (unsigned*)(idx + BS_TOK);
  float* table = (float*)cand;  // overlay; written only after refine

  // zf16 packed rows [hi 512 | lo 512] live in the zq output region
  _Float16* zf16 = (_Float16*)zq;

  // 0) split weights
  k_split_w<<<DIM * DIM / 1024, 256, 0, stream>>>(W_in, winhi, winlo);
  k_split_w<<<DIM * DIM / 1024, 256, 0, stream>>>(W_out, wouthi, woutlo);
  // 1) normalize + split codebook rows -> ws
  k_rownorm_split<<<NCODE, 256, 0, stream>>>(emb, embhi, emblo, DIM);
  // 2) zf16 = split(z @ W_in^T + b_in)  (UNNORMALIZED; fused epilogue)
  k_gemm_mfma_in<<<dim3(DIM / 128, BS_TOK / 128), 256, 0, stream>>>(
      z, winhi, winlo, b_in, zf16);
  // 3) hi-only MFMA similarity -> top-4 candidates per (token, quarter)
  k_sim_argmax<<<(BS_TOK / SIMK_BM) * NQUART, 256, 0, stream>>>(zf16, embhi,
                                                                cand);
  // 4) exact refine -> idx (ws) + idxf (d_out)
  k_refine<<<BS_TOK / 4, 256, 0, stream>>>(cand, zf16, embhi, emblo, idx,
                                           idxf);
  // 5) codebook output table (2048 rows; overlays dead cand region)
  k_gemm_codebook<<<dim3(DIM / 128, NCODE / 128), 256, 0, stream>>>(
      embhi, emblo, wouthi, woutlo, b_out, table);
  // 6) zq = z + (table[idx] - z)  (overwrites zf16 region)
  k_gather_st<<<BS_TOK * (DIM / 4) / 256, 256, 0, stream>>>(z, table, idx,
                                                            zq);
}